// Round 5
// baseline (659.864 us; speedup 1.0000x reference)
//
#include <hip/hip_runtime.h>
#include <hip/hip_bf16.h>
#include <hip/hip_fp16.h>

#define N_NODES 50000
#define N_EDGES 800000
#define IN_CH 64
#define EDGE_DIM 8
#define HIDDEN 128
#define NUM_GRAPHS 256

// ===========================================================================
// CSR build: histogram of dst, exclusive scan, scatter edge ids.
// ===========================================================================
__global__ __launch_bounds__(256) void hist_kernel(
    const int* __restrict__ dst, int* __restrict__ deg, int E)
{
    int i = blockIdx.x * blockDim.x + threadIdx.x;
    if (i < E) atomicAdd(&deg[dst[i]], 1);
}

__global__ __launch_bounds__(256) void scan1_kernel(
    const int* __restrict__ deg, int* __restrict__ incl,
    int* __restrict__ blockSums, int N)
{
    __shared__ int s[256];
    int b = blockIdx.x, t = threadIdx.x;
    int i0 = b * 512 + 2 * t;
    int a0 = (i0 < N) ? deg[i0] : 0;
    int a1 = (i0 + 1 < N) ? deg[i0 + 1] : 0;
    int ps = a0 + a1;
    s[t] = ps;
    __syncthreads();
    for (int off = 1; off < 256; off <<= 1) {
        int v = (t >= off) ? s[t - off] : 0;
        __syncthreads();
        s[t] += v;
        __syncthreads();
    }
    int exclp = s[t] - ps;
    if (i0 < N)     incl[i0]     = exclp + a0;
    if (i0 + 1 < N) incl[i0 + 1] = exclp + a0 + a1;
    if (t == 255) blockSums[b] = s[255];
}

__global__ __launch_bounds__(128) void scan2_kernel(int* __restrict__ blockSums, int B)
{
    __shared__ int s[128];
    int t = threadIdx.x;
    int v = (t < B) ? blockSums[t] : 0;
    s[t] = v;
    __syncthreads();
    for (int off = 1; off < 128; off <<= 1) {
        int u = (t >= off) ? s[t - off] : 0;
        __syncthreads();
        s[t] += u;
        __syncthreads();
    }
    if (t < B) blockSums[t] = s[t] - v;   // exclusive
}

__global__ __launch_bounds__(256) void scan3_kernel(
    const int* __restrict__ incl, const int* __restrict__ deg,
    const int* __restrict__ blockSums, int* __restrict__ rowptr,
    int* __restrict__ pos, int N)
{
    int i = blockIdx.x * blockDim.x + threadIdx.x;
    if (i >= N) return;
    int v = incl[i] - deg[i] + blockSums[i >> 9];
    rowptr[i] = v;
    pos[i] = v;
}

__global__ __launch_bounds__(256) void scatter_kernel(
    const int* __restrict__ dst, int* __restrict__ pos,
    int* __restrict__ eid, int E)
{
    int e = blockIdx.x * blockDim.x + threadIdx.x;
    if (e >= E) return;
    int p = atomicAdd(&pos[dst[e]], 1);
    eid[p] = e;
}

// Pre-gather edge data into CSR order: src_s[i] = src[eid[i]], ea_s[i] = ea[eid[i]]
__global__ __launch_bounds__(256) void edge_gather_kernel(
    const int* __restrict__ eid, const int* __restrict__ src,
    const float* __restrict__ ea,
    int* __restrict__ src_s, float* __restrict__ ea_s, int E)
{
    int i = blockIdx.x * blockDim.x + threadIdx.x;
    if (i >= E) return;
    int e = eid[i];
    src_s[i] = src[e];
    const float4* p = (const float4*)(ea + (size_t)e * EDGE_DIM);
    float4 a = p[0], b = p[1];
    float4* q = (float4*)(ea_s + (size_t)i * EDGE_DIM);
    q[0] = a; q[1] = b;
}

// fp32 -> fp16 conversion for the gather input
__global__ __launch_bounds__(256) void cvt_half_kernel(
    const float* __restrict__ x, __half* __restrict__ xh, int n)
{
    int i = blockIdx.x * blockDim.x + threadIdx.x;
    if (i < n) xh[i] = __float2half(x[i]);
}

// ===========================================================================
// Node-centric gather-aggregate, fused self term.
//   xs[n][j] = h[n][j] + sum over incoming e: relu( h[src][j] + (ea@We+be)[j] )
// h is fp16 (halves fabric traffic); edge data pre-sorted to CSR order so
// staging loads are contiguous. D threads per block.
// ===========================================================================
template<int D>
__global__ __launch_bounds__(128) void gather_xs_kernel(
    const __half* __restrict__ h,       // [N, D] fp16
    const int*    __restrict__ src_s,   // [E] CSR-ordered src
    const float*  __restrict__ ea_s,    // [E, 8] CSR-ordered edge attrs
    const int*    __restrict__ rowptr,  // [N]
    const int*    __restrict__ deg,     // [N]
    const float*  __restrict__ We,      // [8, D]
    const float*  __restrict__ be,      // [D]
    float*        __restrict__ xs,      // [N, D] fp32 output: h + agg
    int N)
{
    const int CH = 128;                 // edges staged per chunk
    __shared__ int   s_src[CH];
    __shared__ float s_ea[CH * 8];

    int n = blockIdx.x;
    int j = threadIdx.x;   // 0..D-1

    float w[8];
    #pragma unroll
    for (int k = 0; k < 8; ++k) w[k] = We[k * D + j];
    float bej = be[j];

    int start = rowptr[n];
    int dg = deg[n];

    float acc = __half2float(h[(size_t)n * D + j]);   // self term (eps = 0)

    const float4* g_ea4 = (const float4*)ea_s;

    for (int base = 0; base < dg; base += CH) {
        int cnt = dg - base;
        if (cnt > CH) cnt = CH;
        // contiguous staging of src ids and edge attrs
        for (int t = j; t < cnt; t += D) s_src[t] = src_s[start + base + t];
        size_t eb2 = (size_t)(start + base) * 2;
        for (int t = j; t < cnt * 2; t += D) ((float4*)s_ea)[t] = g_ea4[eb2 + t];
        __syncthreads();

        for (int p = 0; p < cnt; ++p) {
            int s = __builtin_amdgcn_readfirstlane(s_src[p]);   // wave-uniform
            float4 e0 = *(const float4*)&s_ea[p * 8];
            float4 e1 = *(const float4*)&s_ea[p * 8 + 4];
            float m = __half2float(h[(size_t)s * D + j]) + bej
                    + e0.x * w[0] + e0.y * w[1] + e0.z * w[2] + e0.w * w[3]
                    + e1.x * w[4] + e1.y * w[5] + e1.z * w[6] + e1.w * w[7];
            acc += (m > 0.0f) ? m : 0.0f;
        }
        __syncthreads();
    }
    xs[(size_t)n * D + j] = acc;
}

// ===========================================================================
// Node GEMM: out[n][j] = relu( b[j] + sum_k xs[n][k] * W[k][j] ), out in fp16
// 256 threads, 16 nodes/block. xs rows wave-uniform -> scalar loads.
// ===========================================================================
template<int DIN>
__global__ __launch_bounds__(256, 4) void node_kernel(
    const float* __restrict__ xs,    // [N, DIN] fp32
    const float* __restrict__ W,     // [DIN, 128]
    const float* __restrict__ b,     // [128]
    __half*      __restrict__ out,   // [N, 128] fp16
    int N)
{
    const int NPH = 8;
    int j    = threadIdx.x & 127;
    int half = threadIdx.x >> 7;
    int n0   = blockIdx.x * 16 + half * NPH;

    float bj = b[j];
    float acc[NPH];
    #pragma unroll
    for (int i = 0; i < NPH; ++i) acc[i] = bj;

    const float* row[NPH];
    #pragma unroll
    for (int i = 0; i < NPH; ++i) {
        int off = __builtin_amdgcn_readfirstlane((n0 + i) * DIN);
        row[i] = xs + off;
    }

    for (int k = 0; k < DIN; k += 4) {
        float w0 = W[(k + 0) * HIDDEN + j];
        float w1 = W[(k + 1) * HIDDEN + j];
        float w2 = W[(k + 2) * HIDDEN + j];
        float w3 = W[(k + 3) * HIDDEN + j];
        #pragma unroll
        for (int i = 0; i < NPH; ++i) {
            float4 xv = *(const float4*)(row[i] + k);
            acc[i] = fmaf(xv.x, w0, acc[i]);
            acc[i] = fmaf(xv.y, w1, acc[i]);
            acc[i] = fmaf(xv.z, w2, acc[i]);
            acc[i] = fmaf(xv.w, w3, acc[i]);
        }
    }

    #pragma unroll
    for (int i = 0; i < NPH; ++i) {
        int n = n0 + i;
        float v = acc[i];
        out[(size_t)n * HIDDEN + j] = __float2half(v > 0.0f ? v : 0.0f);
    }
}

// ===========================================================================
// Pool: batch sorted -> one block per graph, binary-search range, direct sum.
// ===========================================================================
__global__ __launch_bounds__(128) void pool_kernel(
    const __half* __restrict__ h,      // [N, 128] fp16
    const int*    __restrict__ batch,  // [N] sorted
    float*        __restrict__ out,    // [G, 128]
    int N)
{
    __shared__ int s_lo, s_hi;
    int g = blockIdx.x;
    int j = threadIdx.x;

    if (j == 0) {
        int lo = 0, hi = N;
        while (lo < hi) { int m = (lo + hi) >> 1; if (batch[m] < g) lo = m + 1; else hi = m; }
        s_lo = lo;
        int lo2 = lo, hi2 = N;
        while (lo2 < hi2) { int m = (lo2 + hi2) >> 1; if (batch[m] < g + 1) lo2 = m + 1; else hi2 = m; }
        s_hi = lo2;
    }
    __syncthreads();

    int lo = s_lo, hi = s_hi;
    float acc = 0.0f;
    #pragma unroll 4
    for (int n = lo; n < hi; ++n) {
        acc += __half2float(h[(size_t)n * HIDDEN + j]);
    }
    float c = (float)(hi - lo);
    out[g * HIDDEN + j] = acc / (c > 1.0f ? c : 1.0f);
}

// ===========================================================================
extern "C" void kernel_launch(void* const* d_in, const int* in_sizes, int n_in,
                              void* d_out, int out_size, void* d_ws, size_t ws_size,
                              hipStream_t stream)
{
    const float* x   = (const float*)d_in[0];      // [N, 64]
    const int*   ei  = (const int*)d_in[1];        // [2, E]
    const float* ea  = (const float*)d_in[2];      // [E, 8]
    const int*   bat = (const int*)d_in[3];        // [N]
    const float* W1  = (const float*)d_in[4];
    const float* b1  = (const float*)d_in[5];
    const float* We1 = (const float*)d_in[6];
    const float* be1 = (const float*)d_in[7];
    const float* W2  = (const float*)d_in[8];
    const float* b2  = (const float*)d_in[9];
    const float* We2 = (const float*)d_in[10];
    const float* be2 = (const float*)d_in[11];
    const float* W3  = (const float*)d_in[12];
    const float* b3  = (const float*)d_in[13];
    const float* We3 = (const float*)d_in[14];
    const float* be3 = (const float*)d_in[15];
    float* out = (float*)d_out;

    const int* src = ei;
    const int* dst = ei + N_EDGES;

    // ---------------- workspace layout ----------------
    int* deg       = (int*)d_ws;                             // [N]
    int* rowptr    = deg + N_NODES;                          // [N]
    int* pos       = rowptr + N_NODES;                       // [N]
    int* eid       = pos + N_NODES;                          // [E]
    int* src_s     = eid + N_EDGES;                          // [E]
    int* blockSums = src_s + N_EDGES;                        // [128]
    float* ea_s    = (float*)(blockSums + 128);              // [E, 8]
    float* xs      = ea_s + (size_t)N_EDGES * EDGE_DIM;      // [N, 128] fp32
    __half* xh     = (__half*)(xs + (size_t)N_NODES * HIDDEN);  // [N, 64] fp16
    __half* h1h    = xh + (size_t)N_NODES * IN_CH;           // [N, 128] fp16
    __half* h2h    = h1h + (size_t)N_NODES * HIDDEN;         // [N, 128] fp16

    const int BLK = 256;
    const int NB_E = (N_EDGES + BLK - 1) / BLK;
    const int NB_N = (N_NODES + BLK - 1) / BLK;
    const int SCAN_B = (N_NODES + 511) / 512;    // 98

    // ---------------- CSR build + edge pre-sort (once) ----------------
    hipMemsetAsync(deg, 0, N_NODES * sizeof(int), stream);
    hist_kernel<<<NB_E, BLK, 0, stream>>>(dst, deg, N_EDGES);
    scan1_kernel<<<SCAN_B, 256, 0, stream>>>(deg, pos, blockSums, N_NODES);
    scan2_kernel<<<1, 128, 0, stream>>>(blockSums, SCAN_B);
    scan3_kernel<<<NB_N, BLK, 0, stream>>>(pos, deg, blockSums, rowptr, pos, N_NODES);
    scatter_kernel<<<NB_E, BLK, 0, stream>>>(dst, pos, eid, N_EDGES);
    edge_gather_kernel<<<NB_E, BLK, 0, stream>>>(eid, src, ea, src_s, ea_s, N_EDGES);
    cvt_half_kernel<<<(N_NODES * IN_CH + BLK - 1) / BLK, BLK, 0, stream>>>(x, xh, N_NODES * IN_CH);

    // ---------------- layer 1 (64 -> 128) ----------------
    gather_xs_kernel<IN_CH><<<N_NODES, IN_CH, 0, stream>>>(
        xh, src_s, ea_s, rowptr, deg, We1, be1, xs, N_NODES);
    node_kernel<IN_CH><<<N_NODES / 16, 256, 0, stream>>>(xs, W1, b1, h1h, N_NODES);

    // ---------------- layer 2 (128 -> 128) ----------------
    gather_xs_kernel<HIDDEN><<<N_NODES, HIDDEN, 0, stream>>>(
        h1h, src_s, ea_s, rowptr, deg, We2, be2, xs, N_NODES);
    node_kernel<HIDDEN><<<N_NODES / 16, 256, 0, stream>>>(xs, W2, b2, h2h, N_NODES);

    // ---------------- layer 3 (128 -> 128) ----------------
    gather_xs_kernel<HIDDEN><<<N_NODES, HIDDEN, 0, stream>>>(
        h2h, src_s, ea_s, rowptr, deg, We3, be3, xs, N_NODES);
    node_kernel<HIDDEN><<<N_NODES / 16, 256, 0, stream>>>(xs, W3, b3, h1h, N_NODES);

    // ---------------- global mean pool ----------------
    pool_kernel<<<NUM_GRAPHS, 128, 0, stream>>>(h1h, bat, out, N_NODES);
}

// Round 6
// 654.633 us; speedup vs baseline: 1.0080x; 1.0080x over previous
//
#include <hip/hip_runtime.h>
#include <hip/hip_bf16.h>
#include <hip/hip_fp16.h>

#define N_NODES 50000
#define N_EDGES 800000
#define IN_CH 64
#define EDGE_DIM 8
#define HIDDEN 128
#define NUM_GRAPHS 256

// ===========================================================================
// CSR build: histogram of dst, exclusive scan, fused scatter+edge-gather.
// ===========================================================================
__global__ __launch_bounds__(256) void hist_kernel(
    const int* __restrict__ dst, int* __restrict__ deg, int E)
{
    int i = blockIdx.x * blockDim.x + threadIdx.x;
    if (i < E) atomicAdd(&deg[dst[i]], 1);
}

__global__ __launch_bounds__(256) void scan1_kernel(
    const int* __restrict__ deg, int* __restrict__ incl,
    int* __restrict__ blockSums, int N)
{
    __shared__ int s[256];
    int b = blockIdx.x, t = threadIdx.x;
    int i0 = b * 512 + 2 * t;
    int a0 = (i0 < N) ? deg[i0] : 0;
    int a1 = (i0 + 1 < N) ? deg[i0 + 1] : 0;
    int ps = a0 + a1;
    s[t] = ps;
    __syncthreads();
    for (int off = 1; off < 256; off <<= 1) {
        int v = (t >= off) ? s[t - off] : 0;
        __syncthreads();
        s[t] += v;
        __syncthreads();
    }
    int exclp = s[t] - ps;
    if (i0 < N)     incl[i0]     = exclp + a0;
    if (i0 + 1 < N) incl[i0 + 1] = exclp + a0 + a1;
    if (t == 255) blockSums[b] = s[255];
}

__global__ __launch_bounds__(128) void scan2_kernel(int* __restrict__ blockSums, int B)
{
    __shared__ int s[128];
    int t = threadIdx.x;
    int v = (t < B) ? blockSums[t] : 0;
    s[t] = v;
    __syncthreads();
    for (int off = 1; off < 128; off <<= 1) {
        int u = (t >= off) ? s[t - off] : 0;
        __syncthreads();
        s[t] += u;
        __syncthreads();
    }
    if (t < B) blockSums[t] = s[t] - v;   // exclusive
}

__global__ __launch_bounds__(256) void scan3_kernel(
    const int* __restrict__ incl, const int* __restrict__ deg,
    const int* __restrict__ blockSums, int* __restrict__ rowptr,
    int* __restrict__ pos, int N)
{
    int i = blockIdx.x * blockDim.x + threadIdx.x;
    if (i >= N) return;
    int v = incl[i] - deg[i] + blockSums[i >> 9];
    rowptr[i] = v;
    pos[i] = v;
}

// fused: place src and ea directly into CSR order (no eid round-trip)
__global__ __launch_bounds__(256) void scatter_fused_kernel(
    const int* __restrict__ dst, const int* __restrict__ src,
    const float* __restrict__ ea, int* __restrict__ pos,
    int* __restrict__ src_s, float* __restrict__ ea_s, int E)
{
    int e = blockIdx.x * blockDim.x + threadIdx.x;
    if (e >= E) return;
    int p = atomicAdd(&pos[dst[e]], 1);
    src_s[p] = src[e];
    const float4* q = (const float4*)(ea + (size_t)e * EDGE_DIM);
    float4 a = q[0], b = q[1];
    float4* o = (float4*)(ea_s + (size_t)p * EDGE_DIM);
    o[0] = a; o[1] = b;
}

// fp32 -> fp16 conversion for the gather input
__global__ __launch_bounds__(256) void cvt_half_kernel(
    const float* __restrict__ x, __half* __restrict__ xh, int n)
{
    int i = blockIdx.x * blockDim.x + threadIdx.x;
    if (i < n) xh[i] = __float2half(x[i]);
}

// ===========================================================================
// Gather-aggregate, D=128: one block = 64 threads = 1 wave = 1 node.
// Each lane handles 2 features (half2 loads). Edge src/ea are wave-uniform:
// src via readfirstlane -> SGPR; ea via uniform float4 loads. NO LDS.
//   xs[n][j] = h[n][j] + sum_e relu( h[src][j] + (ea@We+be)[j] )
// ===========================================================================
__global__ __launch_bounds__(64) void gather_xs128_kernel(
    const __half* __restrict__ h,       // [N,128] fp16
    const int*    __restrict__ src_s,   // [E] CSR order
    const float*  __restrict__ ea_s,    // [E,8] CSR order
    const int*    __restrict__ rowptr,  // [N]
    const int*    __restrict__ deg,     // [N]
    const float*  __restrict__ We,      // [8,128]
    const float*  __restrict__ be,      // [128]
    float*        __restrict__ xs,      // [N,128] fp32
    int N)
{
    int n  = blockIdx.x;
    int l  = threadIdx.x;       // 0..63
    int j0 = 2 * l;

    float w0[8], w1[8];
    #pragma unroll
    for (int k = 0; k < 8; ++k) {
        float2 wv = *(const float2*)&We[k * 128 + j0];
        w0[k] = wv.x; w1[k] = wv.y;
    }
    float2 bev = *(const float2*)&be[j0];

    int start = __builtin_amdgcn_readfirstlane(rowptr[n]);
    int dg    = __builtin_amdgcn_readfirstlane(deg[n]);

    float2 hf = __half22float2(*(const __half2*)&h[(size_t)n * 128 + j0]);
    float acc0 = hf.x, acc1 = hf.y;   // self term (eps = 0)

    #pragma unroll 2
    for (int p = 0; p < dg; ++p) {
        int idx = start + p;
        int s = __builtin_amdgcn_readfirstlane(src_s[idx]);   // uniform
        float4 e0 = *(const float4*)&ea_s[(size_t)idx * 8];   // uniform
        float4 e1 = *(const float4*)&ea_s[(size_t)idx * 8 + 4];
        float2 hs = __half22float2(*(const __half2*)&h[(size_t)s * 128 + j0]);

        // two independent FMA chains per feature for ILP
        float a0 = fmaf(e0.x, w0[0], fmaf(e0.y, w0[1], fmaf(e0.z, w0[2], fmaf(e0.w, w0[3], bev.x))));
        float c0 = fmaf(e1.x, w0[4], fmaf(e1.y, w0[5], fmaf(e1.z, w0[6], e1.w * w0[7])));
        float a1 = fmaf(e0.x, w1[0], fmaf(e0.y, w1[1], fmaf(e0.z, w1[2], fmaf(e0.w, w1[3], bev.y))));
        float c1 = fmaf(e1.x, w1[4], fmaf(e1.y, w1[5], fmaf(e1.z, w1[6], e1.w * w1[7])));
        float m0 = hs.x + a0 + c0;
        float m1 = hs.y + a1 + c1;
        acc0 += m0 > 0.0f ? m0 : 0.0f;
        acc1 += m1 > 0.0f ? m1 : 0.0f;
    }
    *(float2*)&xs[(size_t)n * 128 + j0] = make_float2(acc0, acc1);
}

// D=64 variant: 64 threads, 1 feature per lane.
__global__ __launch_bounds__(64) void gather_xs64_kernel(
    const __half* __restrict__ h,       // [N,64] fp16
    const int*    __restrict__ src_s,
    const float*  __restrict__ ea_s,
    const int*    __restrict__ rowptr,
    const int*    __restrict__ deg,
    const float*  __restrict__ We,      // [8,64]
    const float*  __restrict__ be,      // [64]
    float*        __restrict__ xs,      // [N,64] fp32
    int N)
{
    int n = blockIdx.x;
    int j = threadIdx.x;   // 0..63

    float w[8];
    #pragma unroll
    for (int k = 0; k < 8; ++k) w[k] = We[k * 64 + j];
    float bej = be[j];

    int start = __builtin_amdgcn_readfirstlane(rowptr[n]);
    int dg    = __builtin_amdgcn_readfirstlane(deg[n]);

    float acc = __half2float(h[(size_t)n * 64 + j]);   // self term

    #pragma unroll 2
    for (int p = 0; p < dg; ++p) {
        int idx = start + p;
        int s = __builtin_amdgcn_readfirstlane(src_s[idx]);
        float4 e0 = *(const float4*)&ea_s[(size_t)idx * 8];
        float4 e1 = *(const float4*)&ea_s[(size_t)idx * 8 + 4];
        float hs = __half2float(h[(size_t)s * 64 + j]);

        float a = fmaf(e0.x, w[0], fmaf(e0.y, w[1], fmaf(e0.z, w[2], fmaf(e0.w, w[3], bej))));
        float c = fmaf(e1.x, w[4], fmaf(e1.y, w[5], fmaf(e1.z, w[6], e1.w * w[7])));
        float m = hs + a + c;
        acc += m > 0.0f ? m : 0.0f;
    }
    xs[(size_t)n * 64 + j] = acc;
}

// ===========================================================================
// Node GEMM: out[n][j] = relu( b[j] + sum_k xs[n][k] * W[k][j] ), out fp16.
// 256 threads, 32 nodes/block (16 per half). xs rows wave-uniform -> scalar
// loads; W columns coalesced vector loads.
// ===========================================================================
template<int DIN>
__global__ __launch_bounds__(256, 4) void node_kernel(
    const float* __restrict__ xs,    // [N, DIN] fp32
    const float* __restrict__ W,     // [DIN, 128]
    const float* __restrict__ b,     // [128]
    __half*      __restrict__ out,   // [N, 128] fp16
    int N)
{
    const int NPH = 16;
    int j    = threadIdx.x & 127;
    int half = threadIdx.x >> 7;
    int n0   = blockIdx.x * 32 + half * NPH;

    float bj = b[j];
    float acc[NPH];
    #pragma unroll
    for (int i = 0; i < NPH; ++i) acc[i] = bj;

    const float* row[NPH];
    #pragma unroll
    for (int i = 0; i < NPH; ++i) {
        int off = __builtin_amdgcn_readfirstlane((n0 + i) * DIN);
        row[i] = xs + off;
    }

    for (int k = 0; k < DIN; k += 4) {
        float w0 = W[(k + 0) * HIDDEN + j];
        float w1 = W[(k + 1) * HIDDEN + j];
        float w2 = W[(k + 2) * HIDDEN + j];
        float w3 = W[(k + 3) * HIDDEN + j];
        #pragma unroll
        for (int i = 0; i < NPH; ++i) {
            float4 xv = *(const float4*)(row[i] + k);
            acc[i] = fmaf(xv.x, w0, acc[i]);
            acc[i] = fmaf(xv.y, w1, acc[i]);
            acc[i] = fmaf(xv.z, w2, acc[i]);
            acc[i] = fmaf(xv.w, w3, acc[i]);
        }
    }

    #pragma unroll
    for (int i = 0; i < NPH; ++i) {
        int n = n0 + i;
        if (n < N) {
            float v = acc[i];
            out[(size_t)n * HIDDEN + j] = __float2half(v > 0.0f ? v : 0.0f);
        }
    }
}

// ===========================================================================
// Pool: batch sorted -> one block per graph, binary-search range, direct sum.
// ===========================================================================
__global__ __launch_bounds__(128) void pool_kernel(
    const __half* __restrict__ h,      // [N, 128] fp16
    const int*    __restrict__ batch,  // [N] sorted
    float*        __restrict__ out,    // [G, 128]
    int N)
{
    __shared__ int s_lo, s_hi;
    int g = blockIdx.x;
    int j = threadIdx.x;

    if (j == 0) {
        int lo = 0, hi = N;
        while (lo < hi) { int m = (lo + hi) >> 1; if (batch[m] < g) lo = m + 1; else hi = m; }
        s_lo = lo;
        int lo2 = lo, hi2 = N;
        while (lo2 < hi2) { int m = (lo2 + hi2) >> 1; if (batch[m] < g + 1) lo2 = m + 1; else hi2 = m; }
        s_hi = lo2;
    }
    __syncthreads();

    int lo = s_lo, hi = s_hi;
    float acc = 0.0f;
    #pragma unroll 4
    for (int n = lo; n < hi; ++n) {
        acc += __half2float(h[(size_t)n * HIDDEN + j]);
    }
    float c = (float)(hi - lo);
    out[g * HIDDEN + j] = acc / (c > 1.0f ? c : 1.0f);
}

// ===========================================================================
extern "C" void kernel_launch(void* const* d_in, const int* in_sizes, int n_in,
                              void* d_out, int out_size, void* d_ws, size_t ws_size,
                              hipStream_t stream)
{
    const float* x   = (const float*)d_in[0];      // [N, 64]
    const int*   ei  = (const int*)d_in[1];        // [2, E]
    const float* ea  = (const float*)d_in[2];      // [E, 8]
    const int*   bat = (const int*)d_in[3];        // [N]
    const float* W1  = (const float*)d_in[4];
    const float* b1  = (const float*)d_in[5];
    const float* We1 = (const float*)d_in[6];
    const float* be1 = (const float*)d_in[7];
    const float* W2  = (const float*)d_in[8];
    const float* b2  = (const float*)d_in[9];
    const float* We2 = (const float*)d_in[10];
    const float* be2 = (const float*)d_in[11];
    const float* W3  = (const float*)d_in[12];
    const float* b3  = (const float*)d_in[13];
    const float* We3 = (const float*)d_in[14];
    const float* be3 = (const float*)d_in[15];
    float* out = (float*)d_out;

    const int* src = ei;
    const int* dst = ei + N_EDGES;

    // ---------------- workspace layout ----------------
    int* deg       = (int*)d_ws;                             // [N]
    int* rowptr    = deg + N_NODES;                          // [N]
    int* pos       = rowptr + N_NODES;                       // [N]
    int* src_s     = pos + N_NODES;                          // [E]
    int* blockSums = src_s + N_EDGES;                        // [128]
    float* ea_s    = (float*)(blockSums + 128);              // [E, 8]
    float* xs      = ea_s + (size_t)N_EDGES * EDGE_DIM;      // [N, 128] fp32
    __half* xh     = (__half*)(xs + (size_t)N_NODES * HIDDEN);  // [N, 64] fp16
    __half* h1h    = xh + (size_t)N_NODES * IN_CH;           // [N, 128] fp16
    __half* h2h    = h1h + (size_t)N_NODES * HIDDEN;         // [N, 128] fp16

    const int BLK = 256;
    const int NB_E = (N_EDGES + BLK - 1) / BLK;
    const int NB_N = (N_NODES + BLK - 1) / BLK;
    const int SCAN_B = (N_NODES + 511) / 512;    // 98
    const int NODE_B = (N_NODES + 31) / 32;      // 1563

    // ---------------- CSR build + edge reorder (once) ----------------
    hipMemsetAsync(deg, 0, N_NODES * sizeof(int), stream);
    hist_kernel<<<NB_E, BLK, 0, stream>>>(dst, deg, N_EDGES);
    scan1_kernel<<<SCAN_B, 256, 0, stream>>>(deg, pos, blockSums, N_NODES);
    scan2_kernel<<<1, 128, 0, stream>>>(blockSums, SCAN_B);
    scan3_kernel<<<NB_N, BLK, 0, stream>>>(pos, deg, blockSums, rowptr, pos, N_NODES);
    scatter_fused_kernel<<<NB_E, BLK, 0, stream>>>(dst, src, ea, pos, src_s, ea_s, N_EDGES);
    cvt_half_kernel<<<(N_NODES * IN_CH + BLK - 1) / BLK, BLK, 0, stream>>>(x, xh, N_NODES * IN_CH);

    // ---------------- layer 1 (64 -> 128) ----------------
    gather_xs64_kernel<<<N_NODES, 64, 0, stream>>>(
        xh, src_s, ea_s, rowptr, deg, We1, be1, xs, N_NODES);
    node_kernel<IN_CH><<<NODE_B, 256, 0, stream>>>(xs, W1, b1, h1h, N_NODES);

    // ---------------- layer 2 (128 -> 128) ----------------
    gather_xs128_kernel<<<N_NODES, 64, 0, stream>>>(
        h1h, src_s, ea_s, rowptr, deg, We2, be2, xs, N_NODES);
    node_kernel<HIDDEN><<<NODE_B, 256, 0, stream>>>(xs, W2, b2, h2h, N_NODES);

    // ---------------- layer 3 (128 -> 128) ----------------
    gather_xs128_kernel<<<N_NODES, 64, 0, stream>>>(
        h2h, src_s, ea_s, rowptr, deg, We3, be3, xs, N_NODES);
    node_kernel<HIDDEN><<<NODE_B, 256, 0, stream>>>(xs, W3, b3, h1h, N_NODES);

    // ---------------- global mean pool ----------------
    pool_kernel<<<NUM_GRAPHS, 128, 0, stream>>>(h1h, bat, out, N_NODES);
}

// Round 8
// 556.235 us; speedup vs baseline: 1.1863x; 1.1769x over previous
//
#include <hip/hip_runtime.h>
#include <hip/hip_bf16.h>
#include <hip/hip_fp16.h>

#define N_NODES 50000
#define N_EDGES 800000
#define IN_CH 64
#define EDGE_DIM 8
#define HIDDEN 128
#define NUM_GRAPHS 256

typedef __attribute__((ext_vector_type(8))) _Float16 half8;
typedef __attribute__((ext_vector_type(4))) float floatx4;

// ===========================================================================
// CSR build: histogram, scan, scatter eids, per-node sort (determinism!),
// then gather edge data into canonical CSR order.
// ===========================================================================
__global__ __launch_bounds__(256) void hist_kernel(
    const int* __restrict__ dst, int* __restrict__ deg, int E)
{
    int i = blockIdx.x * blockDim.x + threadIdx.x;
    if (i < E) atomicAdd(&deg[dst[i]], 1);
}

__global__ __launch_bounds__(256) void scan1_kernel(
    const int* __restrict__ deg, int* __restrict__ incl,
    int* __restrict__ blockSums, int N)
{
    __shared__ int s[256];
    int b = blockIdx.x, t = threadIdx.x;
    int i0 = b * 512 + 2 * t;
    int a0 = (i0 < N) ? deg[i0] : 0;
    int a1 = (i0 + 1 < N) ? deg[i0 + 1] : 0;
    int ps = a0 + a1;
    s[t] = ps;
    __syncthreads();
    for (int off = 1; off < 256; off <<= 1) {
        int v = (t >= off) ? s[t - off] : 0;
        __syncthreads();
        s[t] += v;
        __syncthreads();
    }
    int exclp = s[t] - ps;
    if (i0 < N)     incl[i0]     = exclp + a0;
    if (i0 + 1 < N) incl[i0 + 1] = exclp + a0 + a1;
    if (t == 255) blockSums[b] = s[255];
}

__global__ __launch_bounds__(128) void scan2_kernel(int* __restrict__ blockSums, int B)
{
    __shared__ int s[128];
    int t = threadIdx.x;
    int v = (t < B) ? blockSums[t] : 0;
    s[t] = v;
    __syncthreads();
    for (int off = 1; off < 128; off <<= 1) {
        int u = (t >= off) ? s[t - off] : 0;
        __syncthreads();
        s[t] += u;
        __syncthreads();
    }
    if (t < B) blockSums[t] = s[t] - v;   // exclusive
}

__global__ __launch_bounds__(256) void scan3_kernel(
    const int* __restrict__ incl, const int* __restrict__ deg,
    const int* __restrict__ blockSums, int* __restrict__ rowptr,
    int* __restrict__ pos, int N)
{
    int i = blockIdx.x * blockDim.x + threadIdx.x;
    if (i >= N) return;
    int v = incl[i] - deg[i] + blockSums[i >> 9];
    rowptr[i] = v;
    pos[i] = v;
}

__global__ __launch_bounds__(256) void scatter_kernel(
    const int* __restrict__ dst, int* __restrict__ pos,
    int* __restrict__ eid, int E)
{
    int e = blockIdx.x * blockDim.x + threadIdx.x;
    if (e >= E) return;
    int p = atomicAdd(&pos[dst[e]], 1);
    eid[p] = e;
}

// Deterministic order: sort each node's eid segment ascending (insertion sort,
// one thread per node; avg deg = 16, segments are L2-resident).
__global__ __launch_bounds__(256) void segsort_kernel(
    int* __restrict__ eid, const int* __restrict__ rowptr,
    const int* __restrict__ deg, int N)
{
    int n = blockIdx.x * blockDim.x + threadIdx.x;
    if (n >= N) return;
    int s = rowptr[n], d = deg[n];
    for (int i = 1; i < d; ++i) {
        int key = eid[s + i];
        int j = i - 1;
        while (j >= 0 && eid[s + j] > key) { eid[s + j + 1] = eid[s + j]; --j; }
        eid[s + j + 1] = key;
    }
}

// Materialize src/ea in canonical CSR order.
__global__ __launch_bounds__(256) void edge_gather_kernel(
    const int* __restrict__ eid, const int* __restrict__ src,
    const float* __restrict__ ea,
    int* __restrict__ src_s, float* __restrict__ ea_s, int E)
{
    int i = blockIdx.x * blockDim.x + threadIdx.x;
    if (i >= E) return;
    int e = eid[i];
    src_s[i] = src[e];
    const float4* p = (const float4*)(ea + (size_t)e * EDGE_DIM);
    float4 a = p[0], b = p[1];
    float4* q = (float4*)(ea_s + (size_t)i * EDGE_DIM);
    q[0] = a; q[1] = b;
}

// fp32 -> fp16 conversion
__global__ __launch_bounds__(256) void cvt_half_kernel(
    const float* __restrict__ x, __half* __restrict__ xh, int n)
{
    int i = blockIdx.x * blockDim.x + threadIdx.x;
    if (i < n) xh[i] = __float2half(x[i]);
}

// W [K][128] fp32 -> Wt [128][K] fp16 (transposed for MFMA B-operand loads)
template<int K>
__global__ __launch_bounds__(256) void cvt_wt_kernel(
    const float* __restrict__ W, _Float16* __restrict__ Wt)
{
    int idx = blockIdx.x * blockDim.x + threadIdx.x;
    if (idx >= 128 * K) return;
    int n = idx / K;
    int k = idx - n * K;
    Wt[idx] = (_Float16)W[k * 128 + n];
}

// ===========================================================================
// Gather-aggregate (no LDS; wave-uniform edge data via scalar loads).
//   xs[n][j] = h[n][j] + sum_e relu( h[src][j] + (ea@We+be)[j] )
// Deterministic edge order (sorted CSR). Output fp16 for the MFMA GEMM.
// ===========================================================================
__global__ __launch_bounds__(64) void gather_xs128_kernel(
    const __half* __restrict__ h,       // [N,128] fp16
    const int*    __restrict__ src_s,   // [E] CSR order
    const float*  __restrict__ ea_s,    // [E,8] CSR order
    const int*    __restrict__ rowptr,  // [N]
    const int*    __restrict__ deg,     // [N]
    const float*  __restrict__ We,      // [8,128]
    const float*  __restrict__ be,      // [128]
    __half*       __restrict__ xs,      // [N,128] fp16
    int N)
{
    int n  = blockIdx.x;
    int l  = threadIdx.x;       // 0..63
    int j0 = 2 * l;

    float w0[8], w1[8];
    #pragma unroll
    for (int k = 0; k < 8; ++k) {
        float2 wv = *(const float2*)&We[k * 128 + j0];
        w0[k] = wv.x; w1[k] = wv.y;
    }
    float2 bev = *(const float2*)&be[j0];

    int start = __builtin_amdgcn_readfirstlane(rowptr[n]);
    int dg    = __builtin_amdgcn_readfirstlane(deg[n]);

    float2 hf = __half22float2(*(const __half2*)&h[(size_t)n * 128 + j0]);
    float acc0 = hf.x, acc1 = hf.y;   // self term (eps = 0)

    #pragma unroll 2
    for (int p = 0; p < dg; ++p) {
        int idx = start + p;
        int s = __builtin_amdgcn_readfirstlane(src_s[idx]);   // uniform
        float4 e0 = *(const float4*)&ea_s[(size_t)idx * 8];   // uniform
        float4 e1 = *(const float4*)&ea_s[(size_t)idx * 8 + 4];
        float2 hs = __half22float2(*(const __half2*)&h[(size_t)s * 128 + j0]);

        float a0 = fmaf(e0.x, w0[0], fmaf(e0.y, w0[1], fmaf(e0.z, w0[2], fmaf(e0.w, w0[3], bev.x))));
        float c0 = fmaf(e1.x, w0[4], fmaf(e1.y, w0[5], fmaf(e1.z, w0[6], e1.w * w0[7])));
        float a1 = fmaf(e0.x, w1[0], fmaf(e0.y, w1[1], fmaf(e0.z, w1[2], fmaf(e0.w, w1[3], bev.y))));
        float c1 = fmaf(e1.x, w1[4], fmaf(e1.y, w1[5], fmaf(e1.z, w1[6], e1.w * w1[7])));
        float m0 = hs.x + a0 + c0;
        float m1 = hs.y + a1 + c1;
        acc0 += m0 > 0.0f ? m0 : 0.0f;
        acc1 += m1 > 0.0f ? m1 : 0.0f;
    }
    *(__half2*)&xs[(size_t)n * 128 + j0] = __floats2half2_rn(acc0, acc1);
}

// D=64 variant: 64 threads, 1 feature per lane.
__global__ __launch_bounds__(64) void gather_xs64_kernel(
    const __half* __restrict__ h,       // [N,64] fp16
    const int*    __restrict__ src_s,
    const float*  __restrict__ ea_s,
    const int*    __restrict__ rowptr,
    const int*    __restrict__ deg,
    const float*  __restrict__ We,      // [8,64]
    const float*  __restrict__ be,      // [64]
    __half*       __restrict__ xs,      // [N,64] fp16
    int N)
{
    int n = blockIdx.x;
    int j = threadIdx.x;   // 0..63

    float w[8];
    #pragma unroll
    for (int k = 0; k < 8; ++k) w[k] = We[k * 64 + j];
    float bej = be[j];

    int start = __builtin_amdgcn_readfirstlane(rowptr[n]);
    int dg    = __builtin_amdgcn_readfirstlane(deg[n]);

    float acc = __half2float(h[(size_t)n * 64 + j]);   // self term

    #pragma unroll 2
    for (int p = 0; p < dg; ++p) {
        int idx = start + p;
        int s = __builtin_amdgcn_readfirstlane(src_s[idx]);
        float4 e0 = *(const float4*)&ea_s[(size_t)idx * 8];
        float4 e1 = *(const float4*)&ea_s[(size_t)idx * 8 + 4];
        float hs = __half2float(h[(size_t)s * 64 + j]);

        float a = fmaf(e0.x, w[0], fmaf(e0.y, w[1], fmaf(e0.z, w[2], fmaf(e0.w, w[3], bej))));
        float c = fmaf(e1.x, w[4], fmaf(e1.y, w[5], fmaf(e1.z, w[6], e1.w * w[7])));
        float m = hs + a + c;
        acc += m > 0.0f ? m : 0.0f;
    }
    xs[(size_t)n * 64 + j] = __float2half(acc);
}

// ===========================================================================
// Node GEMM on matrix cores: out = relu(xs @ W + b), fp16 in/out, fp32 acc.
// v_mfma_f32_16x16x32_f16. One wave = 16 nodes x 128 features. 4 waves/block.
// A: A[m=lane&15][k=quad*8+j] -> direct 16B load from xs.
// B: B[k=quad*8+j][n=lane&15] -> direct 16B load from Wt[128][K].
// C/D: col(n)=lane&15, row(m)=quad*4+reg.  (verified layout, m89/m120)
// ===========================================================================
template<int K>
__global__ __launch_bounds__(256) void node_mfma_kernel(
    const _Float16* __restrict__ xs,   // [N,K] fp16
    const _Float16* __restrict__ Wt,   // [128][K] fp16 (W transposed)
    const float*    __restrict__ b,    // [128]
    _Float16*       __restrict__ out,  // [N,128] fp16
    int N)
{
    int wave  = threadIdx.x >> 6;             // 0..3
    int lane  = threadIdx.x & 63;
    int row16 = lane & 15;
    int quad  = lane >> 4;
    int m0    = (blockIdx.x * 4 + wave) * 16; // node base of this wave-tile

    int n_node = m0 + row16;
    if (n_node >= N) n_node = N - 1;          // clamp loads; stores guarded

    floatx4 acc[8];
    #pragma unroll
    for (int t = 0; t < 8; ++t) acc[t] = (floatx4)(0.0f);

    #pragma unroll
    for (int kc = 0; kc < K; kc += 32) {
        half8 a = *(const half8*)&xs[(size_t)n_node * K + kc + quad * 8];
        #pragma unroll
        for (int t = 0; t < 8; ++t) {
            half8 bf = *(const half8*)&Wt[(size_t)(t * 16 + row16) * K + kc + quad * 8];
            acc[t] = __builtin_amdgcn_mfma_f32_16x16x32_f16(a, bf, acc[t], 0, 0, 0);
        }
    }

    #pragma unroll
    for (int t = 0; t < 8; ++t) {
        int col = t * 16 + row16;             // output feature
        float bj = b[col];
        #pragma unroll
        for (int r = 0; r < 4; ++r) {
            int node = m0 + quad * 4 + r;
            if (node < N) {
                float v = acc[t][r] + bj;
                out[(size_t)node * 128 + col] = (_Float16)(v > 0.0f ? v : 0.0f);
            }
        }
    }
}

// ===========================================================================
// Pool: batch sorted -> one block per graph, binary-search range, direct sum.
// ===========================================================================
__global__ __launch_bounds__(128) void pool_kernel(
    const __half* __restrict__ h,      // [N, 128] fp16
    const int*    __restrict__ batch,  // [N] sorted
    float*        __restrict__ out,    // [G, 128]
    int N)
{
    __shared__ int s_lo, s_hi;
    int g = blockIdx.x;
    int j = threadIdx.x;

    if (j == 0) {
        int lo = 0, hi = N;
        while (lo < hi) { int m = (lo + hi) >> 1; if (batch[m] < g) lo = m + 1; else hi = m; }
        s_lo = lo;
        int lo2 = lo, hi2 = N;
        while (lo2 < hi2) { int m = (lo2 + hi2) >> 1; if (batch[m] < g + 1) lo2 = m + 1; else hi2 = m; }
        s_hi = lo2;
    }
    __syncthreads();

    int lo = s_lo, hi = s_hi;
    float acc = 0.0f;
    #pragma unroll 4
    for (int n = lo; n < hi; ++n) {
        acc += __half2float(h[(size_t)n * HIDDEN + j]);
    }
    float c = (float)(hi - lo);
    out[g * HIDDEN + j] = acc / (c > 1.0f ? c : 1.0f);
}

// ===========================================================================
extern "C" void kernel_launch(void* const* d_in, const int* in_sizes, int n_in,
                              void* d_out, int out_size, void* d_ws, size_t ws_size,
                              hipStream_t stream)
{
    const float* x   = (const float*)d_in[0];      // [N, 64]
    const int*   ei  = (const int*)d_in[1];        // [2, E]
    const float* ea  = (const float*)d_in[2];      // [E, 8]
    const int*   bat = (const int*)d_in[3];        // [N]
    const float* W1  = (const float*)d_in[4];
    const float* b1  = (const float*)d_in[5];
    const float* We1 = (const float*)d_in[6];
    const float* be1 = (const float*)d_in[7];
    const float* W2  = (const float*)d_in[8];
    const float* b2  = (const float*)d_in[9];
    const float* We2 = (const float*)d_in[10];
    const float* be2 = (const float*)d_in[11];
    const float* W3  = (const float*)d_in[12];
    const float* b3  = (const float*)d_in[13];
    const float* We3 = (const float*)d_in[14];
    const float* be3 = (const float*)d_in[15];
    float* out = (float*)d_out;

    const int* src = ei;
    const int* dst = ei + N_EDGES;

    // ---------------- workspace layout ----------------
    int* deg       = (int*)d_ws;                             // [N]
    int* rowptr    = deg + N_NODES;                          // [N]
    int* pos       = rowptr + N_NODES;                       // [N]
    int* eid       = pos + N_NODES;                          // [E]
    int* src_s     = eid + N_EDGES;                          // [E]
    int* blockSums = src_s + N_EDGES;                        // [128]
    float* ea_s    = (float*)(blockSums + 128);              // [E, 8]
    __half* xs     = (__half*)(ea_s + (size_t)N_EDGES * EDGE_DIM); // [N,128] fp16
    __half* xh     = xs + (size_t)N_NODES * HIDDEN;          // [N, 64] fp16
    __half* h1h    = xh + (size_t)N_NODES * IN_CH;           // [N, 128] fp16
    __half* h2h    = h1h + (size_t)N_NODES * HIDDEN;         // [N, 128] fp16
    _Float16* Wt1  = (_Float16*)(h2h + (size_t)N_NODES * HIDDEN); // [128,64]
    _Float16* Wt2  = Wt1 + 128 * IN_CH;                      // [128,128]
    _Float16* Wt3  = Wt2 + 128 * HIDDEN;                     // [128,128]

    const int BLK = 256;
    const int NB_E = (N_EDGES + BLK - 1) / BLK;
    const int NB_N = (N_NODES + BLK - 1) / BLK;
    const int SCAN_B = (N_NODES + 511) / 512;    // 98
    const int MFMA_B = (N_NODES + 63) / 64;      // 782 blocks (4 wave-tiles each)

    // ---------------- deterministic CSR build + weight prep ----------------
    hipMemsetAsync(deg, 0, N_NODES * sizeof(int), stream);
    hist_kernel<<<NB_E, BLK, 0, stream>>>(dst, deg, N_EDGES);
    scan1_kernel<<<SCAN_B, 256, 0, stream>>>(deg, pos, blockSums, N_NODES);
    scan2_kernel<<<1, 128, 0, stream>>>(blockSums, SCAN_B);
    scan3_kernel<<<NB_N, BLK, 0, stream>>>(pos, deg, blockSums, rowptr, pos, N_NODES);
    scatter_kernel<<<NB_E, BLK, 0, stream>>>(dst, pos, eid, N_EDGES);
    segsort_kernel<<<NB_N, BLK, 0, stream>>>(eid, rowptr, deg, N_NODES);   // canonical order
    edge_gather_kernel<<<NB_E, BLK, 0, stream>>>(eid, src, ea, src_s, ea_s, N_EDGES);
    cvt_half_kernel<<<(N_NODES * IN_CH + BLK - 1) / BLK, BLK, 0, stream>>>(x, xh, N_NODES * IN_CH);
    cvt_wt_kernel<IN_CH><<<(128 * IN_CH + BLK - 1) / BLK, BLK, 0, stream>>>(W1, Wt1);
    cvt_wt_kernel<HIDDEN><<<(128 * HIDDEN + BLK - 1) / BLK, BLK, 0, stream>>>(W2, Wt2);
    cvt_wt_kernel<HIDDEN><<<(128 * HIDDEN + BLK - 1) / BLK, BLK, 0, stream>>>(W3, Wt3);

    // ---------------- layer 1 (64 -> 128) ----------------
    gather_xs64_kernel<<<N_NODES, 64, 0, stream>>>(
        xh, src_s, ea_s, rowptr, deg, We1, be1, xs, N_NODES);
    node_mfma_kernel<IN_CH><<<MFMA_B, 256, 0, stream>>>(
        (const _Float16*)xs, Wt1, b1, (_Float16*)h1h, N_NODES);

    // ---------------- layer 2 (128 -> 128) ----------------
    gather_xs128_kernel<<<N_NODES, 64, 0, stream>>>(
        h1h, src_s, ea_s, rowptr, deg, We2, be2, xs, N_NODES);
    node_mfma_kernel<HIDDEN><<<MFMA_B, 256, 0, stream>>>(
        (const _Float16*)xs, Wt2, b2, (_Float16*)h2h, N_NODES);

    // ---------------- layer 3 (128 -> 128) ----------------
    gather_xs128_kernel<<<N_NODES, 64, 0, stream>>>(
        h2h, src_s, ea_s, rowptr, deg, We3, be3, xs, N_NODES);
    node_mfma_kernel<HIDDEN><<<MFMA_B, 256, 0, stream>>>(
        (const _Float16*)xs, Wt3, b3, (_Float16*)h1h, N_NODES);

    // ---------------- global mean pool ----------------
    pool_kernel<<<NUM_GRAPHS, 128, 0, stream>>>(h1h, bat, out, N_NODES);
}

// Round 9
// 506.525 us; speedup vs baseline: 1.3027x; 1.0981x over previous
//
#include <hip/hip_runtime.h>
#include <hip/hip_bf16.h>
#include <hip/hip_fp16.h>

#define N_NODES 50000
#define N_EDGES 800000
#define IN_CH 64
#define EDGE_DIM 8
#define HIDDEN 128
#define NUM_GRAPHS 256

typedef __attribute__((ext_vector_type(8))) _Float16 half8;
typedef __attribute__((ext_vector_type(4))) float floatx4;

// ===========================================================================
// CSR build: histogram, scan, scatter eids, per-node sort (determinism!),
// then gather edge data into canonical CSR order.
// ===========================================================================
__global__ __launch_bounds__(256) void hist_kernel(
    const int* __restrict__ dst, int* __restrict__ deg, int E)
{
    int i = blockIdx.x * blockDim.x + threadIdx.x;
    if (i < E) atomicAdd(&deg[dst[i]], 1);
}

__global__ __launch_bounds__(256) void scan1_kernel(
    const int* __restrict__ deg, int* __restrict__ incl,
    int* __restrict__ blockSums, int N)
{
    __shared__ int s[256];
    int b = blockIdx.x, t = threadIdx.x;
    int i0 = b * 512 + 2 * t;
    int a0 = (i0 < N) ? deg[i0] : 0;
    int a1 = (i0 + 1 < N) ? deg[i0 + 1] : 0;
    int ps = a0 + a1;
    s[t] = ps;
    __syncthreads();
    for (int off = 1; off < 256; off <<= 1) {
        int v = (t >= off) ? s[t - off] : 0;
        __syncthreads();
        s[t] += v;
        __syncthreads();
    }
    int exclp = s[t] - ps;
    if (i0 < N)     incl[i0]     = exclp + a0;
    if (i0 + 1 < N) incl[i0 + 1] = exclp + a0 + a1;
    if (t == 255) blockSums[b] = s[255];
}

__global__ __launch_bounds__(128) void scan2_kernel(int* __restrict__ blockSums, int B)
{
    __shared__ int s[128];
    int t = threadIdx.x;
    int v = (t < B) ? blockSums[t] : 0;
    s[t] = v;
    __syncthreads();
    for (int off = 1; off < 128; off <<= 1) {
        int u = (t >= off) ? s[t - off] : 0;
        __syncthreads();
        s[t] += u;
        __syncthreads();
    }
    if (t < B) blockSums[t] = s[t] - v;   // exclusive
}

__global__ __launch_bounds__(256) void scan3_kernel(
    const int* __restrict__ incl, const int* __restrict__ deg,
    const int* __restrict__ blockSums, int* __restrict__ rowptr,
    int* __restrict__ pos, int N)
{
    int i = blockIdx.x * blockDim.x + threadIdx.x;
    if (i >= N) return;
    int v = incl[i] - deg[i] + blockSums[i >> 9];
    rowptr[i] = v;
    pos[i] = v;
}

__global__ __launch_bounds__(256) void scatter_kernel(
    const int* __restrict__ dst, int* __restrict__ pos,
    int* __restrict__ eid, int E)
{
    int e = blockIdx.x * blockDim.x + threadIdx.x;
    if (e >= E) return;
    int p = atomicAdd(&pos[dst[e]], 1);
    eid[p] = e;
}

// Deterministic order: sort each node's eid segment ascending.
__global__ __launch_bounds__(256) void segsort_kernel(
    int* __restrict__ eid, const int* __restrict__ rowptr,
    const int* __restrict__ deg, int N)
{
    int n = blockIdx.x * blockDim.x + threadIdx.x;
    if (n >= N) return;
    int s = rowptr[n], d = deg[n];
    for (int i = 1; i < d; ++i) {
        int key = eid[s + i];
        int j = i - 1;
        while (j >= 0 && eid[s + j] > key) { eid[s + j + 1] = eid[s + j]; --j; }
        eid[s + j + 1] = key;
    }
}

// Materialize src/ea in canonical CSR order.
__global__ __launch_bounds__(256) void edge_gather_kernel(
    const int* __restrict__ eid, const int* __restrict__ src,
    const float* __restrict__ ea,
    int* __restrict__ src_s, float* __restrict__ ea_s, int E)
{
    int i = blockIdx.x * blockDim.x + threadIdx.x;
    if (i >= E) return;
    int e = eid[i];
    src_s[i] = src[e];
    const float4* p = (const float4*)(ea + (size_t)e * EDGE_DIM);
    float4 a = p[0], b = p[1];
    float4* q = (float4*)(ea_s + (size_t)i * EDGE_DIM);
    q[0] = a; q[1] = b;
}

// fp32 -> fp16 conversion
__global__ __launch_bounds__(256) void cvt_half_kernel(
    const float* __restrict__ x, __half* __restrict__ xh, int n)
{
    int i = blockIdx.x * blockDim.x + threadIdx.x;
    if (i < n) xh[i] = __float2half(x[i]);
}

// W [K][128] fp32 -> Wt [128][K] fp16 (transposed for MFMA B-operand loads)
template<int K>
__global__ __launch_bounds__(256) void cvt_wt_kernel(
    const float* __restrict__ W, _Float16* __restrict__ Wt)
{
    int idx = blockIdx.x * blockDim.x + threadIdx.x;
    if (idx >= 128 * K) return;
    int n = idx / K;
    int k = idx - n * K;
    Wt[idx] = (_Float16)W[k * 128 + n];
}

// ===========================================================================
// Gather-aggregate, batched for memory-level parallelism (8 edges in flight).
//   xs[n][j] = h[n][j] + sum_e relu( h[src][j] + (ea@We+be)[j] )
// Edge order canonical (sorted CSR) and accumulation order fixed ->
// bit-deterministic. No LDS; src/ea wave-uniform scalar loads.
// ===========================================================================
#define BF 8   // edges in flight per wave

__global__ __launch_bounds__(64) void gather_xs128_kernel(
    const __half* __restrict__ h,       // [N,128] fp16
    const int*    __restrict__ src_s,   // [E] CSR order
    const float*  __restrict__ ea_s,    // [E,8] CSR order
    const int*    __restrict__ rowptr,  // [N]
    const int*    __restrict__ deg,     // [N]
    const float*  __restrict__ We,      // [8,128]
    const float*  __restrict__ be,      // [128]
    __half*       __restrict__ xs,      // [N,128] fp16
    int N)
{
    int n  = blockIdx.x;
    int l  = threadIdx.x;       // 0..63
    int j0 = 2 * l;

    float w0[8], w1[8];
    #pragma unroll
    for (int k = 0; k < 8; ++k) {
        float2 wv = *(const float2*)&We[k * 128 + j0];
        w0[k] = wv.x; w1[k] = wv.y;
    }
    float2 bev = *(const float2*)&be[j0];

    int start = __builtin_amdgcn_readfirstlane(rowptr[n]);
    int dg    = __builtin_amdgcn_readfirstlane(deg[n]);
    int last  = start + dg - 1;

    float2 hf = __half22float2(*(const __half2*)&h[(size_t)n * 128 + j0]);
    float acc0 = hf.x, acc1 = hf.y;   // self term (eps = 0)

    for (int base = 0; base < dg; base += BF) {
        int cnt = dg - base;
        if (cnt > BF) cnt = BF;

        // uniform edge indices (clamped -> always valid loads)
        int idxs[BF];
        #pragma unroll
        for (int t = 0; t < BF; ++t) {
            int idx = start + base + t;
            idxs[t] = idx > last ? last : idx;
        }
        // 8 independent scalar src loads
        int sid[BF];
        #pragma unroll
        for (int t = 0; t < BF; ++t)
            sid[t] = __builtin_amdgcn_readfirstlane(src_s[idxs[t]]);
        // 8 independent vector h-row loads (the latency hiders)
        __half2 hraw[BF];
        #pragma unroll
        for (int t = 0; t < BF; ++t)
            hraw[t] = *(const __half2*)&h[(size_t)sid[t] * 128 + j0];
        // 8 uniform ea loads
        float4 e0[BF], e1[BF];
        #pragma unroll
        for (int t = 0; t < BF; ++t) {
            e0[t] = *(const float4*)&ea_s[(size_t)idxs[t] * 8];
            e1[t] = *(const float4*)&ea_s[(size_t)idxs[t] * 8 + 4];
        }
        // accumulate in fixed order
        #pragma unroll
        for (int t = 0; t < BF; ++t) {
            float2 hs = __half22float2(hraw[t]);
            float a0 = fmaf(e0[t].x, w0[0], fmaf(e0[t].y, w0[1], fmaf(e0[t].z, w0[2], fmaf(e0[t].w, w0[3], bev.x))));
            float c0 = fmaf(e1[t].x, w0[4], fmaf(e1[t].y, w0[5], fmaf(e1[t].z, w0[6], e1[t].w * w0[7])));
            float a1 = fmaf(e0[t].x, w1[0], fmaf(e0[t].y, w1[1], fmaf(e0[t].z, w1[2], fmaf(e0[t].w, w1[3], bev.y))));
            float c1 = fmaf(e1[t].x, w1[4], fmaf(e1[t].y, w1[5], fmaf(e1[t].z, w1[6], e1[t].w * w1[7])));
            float m0 = hs.x + a0 + c0;
            float m1 = hs.y + a1 + c1;
            float r0 = m0 > 0.0f ? m0 : 0.0f;
            float r1 = m1 > 0.0f ? m1 : 0.0f;
            acc0 += (t < cnt) ? r0 : 0.0f;
            acc1 += (t < cnt) ? r1 : 0.0f;
        }
    }
    *(__half2*)&xs[(size_t)n * 128 + j0] = __floats2half2_rn(acc0, acc1);
}

// D=64 variant: 64 threads, 1 feature per lane, same batching.
__global__ __launch_bounds__(64) void gather_xs64_kernel(
    const __half* __restrict__ h,       // [N,64] fp16
    const int*    __restrict__ src_s,
    const float*  __restrict__ ea_s,
    const int*    __restrict__ rowptr,
    const int*    __restrict__ deg,
    const float*  __restrict__ We,      // [8,64]
    const float*  __restrict__ be,      // [64]
    __half*       __restrict__ xs,      // [N,64] fp16
    int N)
{
    int n = blockIdx.x;
    int j = threadIdx.x;   // 0..63

    float w[8];
    #pragma unroll
    for (int k = 0; k < 8; ++k) w[k] = We[k * 64 + j];
    float bej = be[j];

    int start = __builtin_amdgcn_readfirstlane(rowptr[n]);
    int dg    = __builtin_amdgcn_readfirstlane(deg[n]);
    int last  = start + dg - 1;

    float acc = __half2float(h[(size_t)n * 64 + j]);   // self term

    for (int base = 0; base < dg; base += BF) {
        int cnt = dg - base;
        if (cnt > BF) cnt = BF;

        int idxs[BF];
        #pragma unroll
        for (int t = 0; t < BF; ++t) {
            int idx = start + base + t;
            idxs[t] = idx > last ? last : idx;
        }
        int sid[BF];
        #pragma unroll
        for (int t = 0; t < BF; ++t)
            sid[t] = __builtin_amdgcn_readfirstlane(src_s[idxs[t]]);
        __half hraw[BF];
        #pragma unroll
        for (int t = 0; t < BF; ++t)
            hraw[t] = h[(size_t)sid[t] * 64 + j];
        float4 e0[BF], e1[BF];
        #pragma unroll
        for (int t = 0; t < BF; ++t) {
            e0[t] = *(const float4*)&ea_s[(size_t)idxs[t] * 8];
            e1[t] = *(const float4*)&ea_s[(size_t)idxs[t] * 8 + 4];
        }
        #pragma unroll
        for (int t = 0; t < BF; ++t) {
            float hs = __half2float(hraw[t]);
            float a = fmaf(e0[t].x, w[0], fmaf(e0[t].y, w[1], fmaf(e0[t].z, w[2], fmaf(e0[t].w, w[3], bej))));
            float c = fmaf(e1[t].x, w[4], fmaf(e1[t].y, w[5], fmaf(e1[t].z, w[6], e1[t].w * w[7])));
            float m = hs + a + c;
            float r = m > 0.0f ? m : 0.0f;
            acc += (t < cnt) ? r : 0.0f;
        }
    }
    xs[(size_t)n * 64 + j] = __float2half(acc);
}

// ===========================================================================
// Node GEMM on matrix cores: out = relu(xs @ W + b), fp16 in/out, fp32 acc.
// v_mfma_f32_16x16x32_f16. One wave = 16 nodes x 128 features. 4 waves/block.
// ===========================================================================
template<int K>
__global__ __launch_bounds__(256) void node_mfma_kernel(
    const _Float16* __restrict__ xs,   // [N,K] fp16
    const _Float16* __restrict__ Wt,   // [128][K] fp16 (W transposed)
    const float*    __restrict__ b,    // [128]
    _Float16*       __restrict__ out,  // [N,128] fp16
    int N)
{
    int wave  = threadIdx.x >> 6;             // 0..3
    int lane  = threadIdx.x & 63;
    int row16 = lane & 15;
    int quad  = lane >> 4;
    int m0    = (blockIdx.x * 4 + wave) * 16; // node base of this wave-tile

    int n_node = m0 + row16;
    if (n_node >= N) n_node = N - 1;          // clamp loads; stores guarded

    floatx4 acc[8];
    #pragma unroll
    for (int t = 0; t < 8; ++t) acc[t] = (floatx4)(0.0f);

    #pragma unroll
    for (int kc = 0; kc < K; kc += 32) {
        half8 a = *(const half8*)&xs[(size_t)n_node * K + kc + quad * 8];
        #pragma unroll
        for (int t = 0; t < 8; ++t) {
            half8 bf = *(const half8*)&Wt[(size_t)(t * 16 + row16) * K + kc + quad * 8];
            acc[t] = __builtin_amdgcn_mfma_f32_16x16x32_f16(a, bf, acc[t], 0, 0, 0);
        }
    }

    #pragma unroll
    for (int t = 0; t < 8; ++t) {
        int col = t * 16 + row16;             // output feature
        float bj = b[col];
        #pragma unroll
        for (int r = 0; r < 4; ++r) {
            int node = m0 + quad * 4 + r;
            if (node < N) {
                float v = acc[t][r] + bj;
                out[(size_t)node * 128 + col] = (_Float16)(v > 0.0f ? v : 0.0f);
            }
        }
    }
}

// ===========================================================================
// Pool: batch sorted -> one block per graph, binary-search range, direct sum.
// ===========================================================================
__global__ __launch_bounds__(128) void pool_kernel(
    const __half* __restrict__ h,      // [N, 128] fp16
    const int*    __restrict__ batch,  // [N] sorted
    float*        __restrict__ out,    // [G, 128]
    int N)
{
    __shared__ int s_lo, s_hi;
    int g = blockIdx.x;
    int j = threadIdx.x;

    if (j == 0) {
        int lo = 0, hi = N;
        while (lo < hi) { int m = (lo + hi) >> 1; if (batch[m] < g) lo = m + 1; else hi = m; }
        s_lo = lo;
        int lo2 = lo, hi2 = N;
        while (lo2 < hi2) { int m = (lo2 + hi2) >> 1; if (batch[m] < g + 1) lo2 = m + 1; else hi2 = m; }
        s_hi = lo2;
    }
    __syncthreads();

    int lo = s_lo, hi = s_hi;
    float acc = 0.0f;
    #pragma unroll 4
    for (int n = lo; n < hi; ++n) {
        acc += __half2float(h[(size_t)n * HIDDEN + j]);
    }
    float c = (float)(hi - lo);
    out[g * HIDDEN + j] = acc / (c > 1.0f ? c : 1.0f);
}

// ===========================================================================
extern "C" void kernel_launch(void* const* d_in, const int* in_sizes, int n_in,
                              void* d_out, int out_size, void* d_ws, size_t ws_size,
                              hipStream_t stream)
{
    const float* x   = (const float*)d_in[0];      // [N, 64]
    const int*   ei  = (const int*)d_in[1];        // [2, E]
    const float* ea  = (const float*)d_in[2];      // [E, 8]
    const int*   bat = (const int*)d_in[3];        // [N]
    const float* W1  = (const float*)d_in[4];
    const float* b1  = (const float*)d_in[5];
    const float* We1 = (const float*)d_in[6];
    const float* be1 = (const float*)d_in[7];
    const float* W2  = (const float*)d_in[8];
    const float* b2  = (const float*)d_in[9];
    const float* We2 = (const float*)d_in[10];
    const float* be2 = (const float*)d_in[11];
    const float* W3  = (const float*)d_in[12];
    const float* b3  = (const float*)d_in[13];
    const float* We3 = (const float*)d_in[14];
    const float* be3 = (const float*)d_in[15];
    float* out = (float*)d_out;

    const int* src = ei;
    const int* dst = ei + N_EDGES;

    // ---------------- workspace layout ----------------
    int* deg       = (int*)d_ws;                             // [N]
    int* rowptr    = deg + N_NODES;                          // [N]
    int* pos       = rowptr + N_NODES;                       // [N]
    int* eid       = pos + N_NODES;                          // [E]
    int* src_s     = eid + N_EDGES;                          // [E]
    int* blockSums = src_s + N_EDGES;                        // [128]
    float* ea_s    = (float*)(blockSums + 128);              // [E, 8]
    __half* xs     = (__half*)(ea_s + (size_t)N_EDGES * EDGE_DIM); // [N,128] fp16
    __half* xh     = xs + (size_t)N_NODES * HIDDEN;          // [N, 64] fp16
    __half* h1h    = xh + (size_t)N_NODES * IN_CH;           // [N, 128] fp16
    __half* h2h    = h1h + (size_t)N_NODES * HIDDEN;         // [N, 128] fp16
    _Float16* Wt1  = (_Float16*)(h2h + (size_t)N_NODES * HIDDEN); // [128,64]
    _Float16* Wt2  = Wt1 + 128 * IN_CH;                      // [128,128]
    _Float16* Wt3  = Wt2 + 128 * HIDDEN;                     // [128,128]

    const int BLK = 256;
    const int NB_E = (N_EDGES + BLK - 1) / BLK;
    const int NB_N = (N_NODES + BLK - 1) / BLK;
    const int SCAN_B = (N_NODES + 511) / 512;    // 98
    const int MFMA_B = (N_NODES + 63) / 64;      // 782 blocks (4 wave-tiles each)

    // ---------------- deterministic CSR build + weight prep ----------------
    hipMemsetAsync(deg, 0, N_NODES * sizeof(int), stream);
    hist_kernel<<<NB_E, BLK, 0, stream>>>(dst, deg, N_EDGES);
    scan1_kernel<<<SCAN_B, 256, 0, stream>>>(deg, pos, blockSums, N_NODES);
    scan2_kernel<<<1, 128, 0, stream>>>(blockSums, SCAN_B);
    scan3_kernel<<<NB_N, BLK, 0, stream>>>(pos, deg, blockSums, rowptr, pos, N_NODES);
    scatter_kernel<<<NB_E, BLK, 0, stream>>>(dst, pos, eid, N_EDGES);
    segsort_kernel<<<NB_N, BLK, 0, stream>>>(eid, rowptr, deg, N_NODES);   // canonical order
    edge_gather_kernel<<<NB_E, BLK, 0, stream>>>(eid, src, ea, src_s, ea_s, N_EDGES);
    cvt_half_kernel<<<(N_NODES * IN_CH + BLK - 1) / BLK, BLK, 0, stream>>>(x, xh, N_NODES * IN_CH);
    cvt_wt_kernel<IN_CH><<<(128 * IN_CH + BLK - 1) / BLK, BLK, 0, stream>>>(W1, Wt1);
    cvt_wt_kernel<HIDDEN><<<(128 * HIDDEN + BLK - 1) / BLK, BLK, 0, stream>>>(W2, Wt2);
    cvt_wt_kernel<HIDDEN><<<(128 * HIDDEN + BLK - 1) / BLK, BLK, 0, stream>>>(W3, Wt3);

    // ---------------- layer 1 (64 -> 128) ----------------
    gather_xs64_kernel<<<N_NODES, 64, 0, stream>>>(
        xh, src_s, ea_s, rowptr, deg, We1, be1, xs, N_NODES);
    node_mfma_kernel<IN_CH><<<MFMA_B, 256, 0, stream>>>(
        (const _Float16*)xs, Wt1, b1, (_Float16*)h1h, N_NODES);

    // ---------------- layer 2 (128 -> 128) ----------------
    gather_xs128_kernel<<<N_NODES, 64, 0, stream>>>(
        h1h, src_s, ea_s, rowptr, deg, We2, be2, xs, N_NODES);
    node_mfma_kernel<HIDDEN><<<MFMA_B, 256, 0, stream>>>(
        (const _Float16*)xs, Wt2, b2, (_Float16*)h2h, N_NODES);

    // ---------------- layer 3 (128 -> 128) ----------------
    gather_xs128_kernel<<<N_NODES, 64, 0, stream>>>(
        h2h, src_s, ea_s, rowptr, deg, We3, be3, xs, N_NODES);
    node_mfma_kernel<HIDDEN><<<MFMA_B, 256, 0, stream>>>(
        (const _Float16*)xs, Wt3, b3, (_Float16*)h1h, N_NODES);

    // ---------------- global mean pool ----------------
    pool_kernel<<<NUM_GRAPHS, 128, 0, stream>>>(h1h, bat, out, N_NODES);
}

// Round 10
// 468.262 us; speedup vs baseline: 1.4092x; 1.0817x over previous
//
#include <hip/hip_runtime.h>
#include <hip/hip_bf16.h>
#include <hip/hip_fp16.h>

#define N_NODES 50000
#define N_EDGES 800000
#define IN_CH 64
#define EDGE_DIM 8
#define HIDDEN 128
#define NUM_GRAPHS 256

typedef __attribute__((ext_vector_type(8))) _Float16 half8;
typedef __attribute__((ext_vector_type(4))) float floatx4;

static __device__ __forceinline__ __half2 u2h(int u) {
    union { int i; __half2 h; } cv; cv.i = u; return cv.h;
}

// ===========================================================================
// CSR build: histogram, scan, scatter eids, per-node sort (determinism!),
// then gather edge data into canonical CSR order (ea converted to fp16).
// ===========================================================================
__global__ __launch_bounds__(256) void hist_kernel(
    const int* __restrict__ dst, int* __restrict__ deg, int E)
{
    int i = blockIdx.x * blockDim.x + threadIdx.x;
    if (i < E) atomicAdd(&deg[dst[i]], 1);
}

__global__ __launch_bounds__(256) void scan1_kernel(
    const int* __restrict__ deg, int* __restrict__ incl,
    int* __restrict__ blockSums, int N)
{
    __shared__ int s[256];
    int b = blockIdx.x, t = threadIdx.x;
    int i0 = b * 512 + 2 * t;
    int a0 = (i0 < N) ? deg[i0] : 0;
    int a1 = (i0 + 1 < N) ? deg[i0 + 1] : 0;
    int ps = a0 + a1;
    s[t] = ps;
    __syncthreads();
    for (int off = 1; off < 256; off <<= 1) {
        int v = (t >= off) ? s[t - off] : 0;
        __syncthreads();
        s[t] += v;
        __syncthreads();
    }
    int exclp = s[t] - ps;
    if (i0 < N)     incl[i0]     = exclp + a0;
    if (i0 + 1 < N) incl[i0 + 1] = exclp + a0 + a1;
    if (t == 255) blockSums[b] = s[255];
}

__global__ __launch_bounds__(128) void scan2_kernel(int* __restrict__ blockSums, int B)
{
    __shared__ int s[128];
    int t = threadIdx.x;
    int v = (t < B) ? blockSums[t] : 0;
    s[t] = v;
    __syncthreads();
    for (int off = 1; off < 128; off <<= 1) {
        int u = (t >= off) ? s[t - off] : 0;
        __syncthreads();
        s[t] += u;
        __syncthreads();
    }
    if (t < B) blockSums[t] = s[t] - v;   // exclusive
}

__global__ __launch_bounds__(256) void scan3_kernel(
    const int* __restrict__ incl, const int* __restrict__ deg,
    const int* __restrict__ blockSums, int* __restrict__ rowptr,
    int* __restrict__ pos, int N)
{
    int i = blockIdx.x * blockDim.x + threadIdx.x;
    if (i >= N) return;
    int v = incl[i] - deg[i] + blockSums[i >> 9];
    rowptr[i] = v;
    pos[i] = v;
}

__global__ __launch_bounds__(256) void scatter_kernel(
    const int* __restrict__ dst, int* __restrict__ pos,
    int* __restrict__ eid, int E)
{
    int e = blockIdx.x * blockDim.x + threadIdx.x;
    if (e >= E) return;
    int p = atomicAdd(&pos[dst[e]], 1);
    eid[p] = e;
}

// Deterministic order: sort each node's eid segment ascending.
__global__ __launch_bounds__(256) void segsort_kernel(
    int* __restrict__ eid, const int* __restrict__ rowptr,
    const int* __restrict__ deg, int N)
{
    int n = blockIdx.x * blockDim.x + threadIdx.x;
    if (n >= N) return;
    int s = rowptr[n], d = deg[n];
    for (int i = 1; i < d; ++i) {
        int key = eid[s + i];
        int j = i - 1;
        while (j >= 0 && eid[s + j] > key) { eid[s + j + 1] = eid[s + j]; --j; }
        eid[s + j + 1] = key;
    }
}

// Materialize src (int) and ea (fp16, 16B/edge) in canonical CSR order.
__global__ __launch_bounds__(256) void edge_gather_kernel(
    const int* __restrict__ eid, const int* __restrict__ src,
    const float* __restrict__ ea,
    int* __restrict__ src_s, __half* __restrict__ ea16, int E)
{
    int i = blockIdx.x * blockDim.x + threadIdx.x;
    if (i >= E) return;
    int e = eid[i];
    src_s[i] = src[e];
    const float4* p = (const float4*)(ea + (size_t)e * EDGE_DIM);
    float4 a = p[0], b = p[1];
    __half2 q0 = __floats2half2_rn(a.x, a.y);
    __half2 q1 = __floats2half2_rn(a.z, a.w);
    __half2 q2 = __floats2half2_rn(b.x, b.y);
    __half2 q3 = __floats2half2_rn(b.z, b.w);
    __half2* o = (__half2*)(ea16 + (size_t)i * EDGE_DIM);
    o[0] = q0; o[1] = q1; o[2] = q2; o[3] = q3;
}

// fp32 -> fp16 conversion (x input)
__global__ __launch_bounds__(256) void cvt_half_kernel(
    const float* __restrict__ x, __half* __restrict__ xh, int n)
{
    int i = blockIdx.x * blockDim.x + threadIdx.x;
    if (i < n) xh[i] = __float2half(x[i]);
}

// All three W [K][128] fp32 -> Wt [128][K] fp16 in one dispatch.
__global__ __launch_bounds__(256) void cvt_wt_all_kernel(
    const float* __restrict__ W1, const float* __restrict__ W2,
    const float* __restrict__ W3,
    _Float16* __restrict__ Wt1, _Float16* __restrict__ Wt2,
    _Float16* __restrict__ Wt3)
{
    int idx = blockIdx.x * blockDim.x + threadIdx.x;
    if (idx < 128 * IN_CH) {
        int n = idx / IN_CH, k = idx - n * IN_CH;
        Wt1[idx] = (_Float16)W1[k * 128 + n];
        return;
    }
    idx -= 128 * IN_CH;
    if (idx < 128 * HIDDEN) {
        int n = idx / HIDDEN, k = idx - n * HIDDEN;
        Wt2[idx] = (_Float16)W2[k * 128 + n];
        return;
    }
    idx -= 128 * HIDDEN;
    if (idx < 128 * HIDDEN) {
        int n = idx / HIDDEN, k = idx - n * HIDDEN;
        Wt3[idx] = (_Float16)W3[k * 128 + n];
    }
}

// ===========================================================================
// Gather-aggregate, batched (8 edges in flight), packed-fp16 message math.
//   xs[n][j] = h[n][j] + sum_e relu( h[src][j] + (ea@We+be)[j] )
// Canonical sorted-CSR order + fixed accumulate order -> bit-deterministic.
// relu done in fp32 after exact fp16->fp32 widening (commutes).
// ===========================================================================
#define BF 8   // edges in flight per wave

__global__ __launch_bounds__(64) void gather_xs128_kernel(
    const __half* __restrict__ h,       // [N,128] fp16
    const int*    __restrict__ src_s,   // [E] CSR order
    const __half* __restrict__ ea16,    // [E,8] fp16 CSR order
    const int*    __restrict__ rowptr,  // [N]
    const int*    __restrict__ deg,     // [N]
    const float*  __restrict__ We,      // [8,128]
    const float*  __restrict__ be,      // [128]
    __half*       __restrict__ xs,      // [N,128] fp16
    int N)
{
    int n  = blockIdx.x;
    int l  = threadIdx.x;       // 0..63
    int j0 = 2 * l;

    // packed weights: hw[k] = (We[k][j0], We[k][j0+1]) fp16; bias packed fp16
    __half2 hw[8];
    #pragma unroll
    for (int k = 0; k < 8; ++k) {
        float2 wv = *(const float2*)&We[k * 128 + j0];
        hw[k] = __floats2half2_rn(wv.x, wv.y);
    }
    float2 bevf = *(const float2*)&be[j0];
    __half2 bev2 = __floats2half2_rn(bevf.x, bevf.y);

    int start = __builtin_amdgcn_readfirstlane(rowptr[n]);
    int dg    = __builtin_amdgcn_readfirstlane(deg[n]);
    int last  = start + dg - 1;

    float2 hf = __half22float2(*(const __half2*)&h[(size_t)n * 128 + j0]);
    float acc0 = hf.x, acc1 = hf.y;   // self term (eps = 0)

    for (int base = 0; base < dg; base += BF) {
        int cnt = dg - base;
        if (cnt > BF) cnt = BF;

        int idxs[BF];
        #pragma unroll
        for (int t = 0; t < BF; ++t) {
            int idx = start + base + t;
            idxs[t] = idx > last ? last : idx;
        }
        int sid[BF];
        #pragma unroll
        for (int t = 0; t < BF; ++t)
            sid[t] = __builtin_amdgcn_readfirstlane(src_s[idxs[t]]);
        __half2 hraw[BF];                 // random 4B/lane loads, the latency hiders
        #pragma unroll
        for (int t = 0; t < BF; ++t)
            hraw[t] = *(const __half2*)&h[(size_t)sid[t] * 128 + j0];
        int4 eav[BF];                     // uniform 16B edge-attr loads
        #pragma unroll
        for (int t = 0; t < BF; ++t)
            eav[t] = *(const int4*)&ea16[(size_t)idxs[t] * 8];

        #pragma unroll
        for (int t = 0; t < BF; ++t) {
            __half2 e01 = u2h(eav[t].x), e23 = u2h(eav[t].y);
            __half2 e45 = u2h(eav[t].z), e67 = u2h(eav[t].w);
            __half2 m = __hfma2(__low2half2(e01),  hw[0], bev2);
            m = __hfma2(__high2half2(e01), hw[1], m);
            m = __hfma2(__low2half2(e23),  hw[2], m);
            m = __hfma2(__high2half2(e23), hw[3], m);
            m = __hfma2(__low2half2(e45),  hw[4], m);
            m = __hfma2(__high2half2(e45), hw[5], m);
            m = __hfma2(__low2half2(e67),  hw[6], m);
            m = __hfma2(__high2half2(e67), hw[7], m);
            m = __hadd2(m, hraw[t]);
            float2 mf = __half22float2(m);
            float r0 = mf.x > 0.0f ? mf.x : 0.0f;
            float r1 = mf.y > 0.0f ? mf.y : 0.0f;
            acc0 += (t < cnt) ? r0 : 0.0f;
            acc1 += (t < cnt) ? r1 : 0.0f;
        }
    }
    *(__half2*)&xs[(size_t)n * 128 + j0] = __floats2half2_rn(acc0, acc1);
}

// D=64: 1 feature/lane; projection via k-packed fp16 dot (4 pk_fma + h-add).
__global__ __launch_bounds__(64) void gather_xs64_kernel(
    const __half* __restrict__ h,       // [N,64] fp16
    const int*    __restrict__ src_s,
    const __half* __restrict__ ea16,    // [E,8] fp16
    const int*    __restrict__ rowptr,
    const int*    __restrict__ deg,
    const float*  __restrict__ We,      // [8,64]
    const float*  __restrict__ be,      // [64]
    __half*       __restrict__ xs,      // [N,64] fp16
    int N)
{
    int n = blockIdx.x;
    int j = threadIdx.x;   // 0..63

    // k-packed weights for this feature column: w2[p] = (We[2p][j], We[2p+1][j])
    __half2 w2[4];
    #pragma unroll
    for (int p = 0; p < 4; ++p)
        w2[p] = __floats2half2_rn(We[(2 * p) * 64 + j], We[(2 * p + 1) * 64 + j]);
    float bej = be[j];

    int start = __builtin_amdgcn_readfirstlane(rowptr[n]);
    int dg    = __builtin_amdgcn_readfirstlane(deg[n]);
    int last  = start + dg - 1;

    float acc = __half2float(h[(size_t)n * 64 + j]);   // self term

    for (int base = 0; base < dg; base += BF) {
        int cnt = dg - base;
        if (cnt > BF) cnt = BF;

        int idxs[BF];
        #pragma unroll
        for (int t = 0; t < BF; ++t) {
            int idx = start + base + t;
            idxs[t] = idx > last ? last : idx;
        }
        int sid[BF];
        #pragma unroll
        for (int t = 0; t < BF; ++t)
            sid[t] = __builtin_amdgcn_readfirstlane(src_s[idxs[t]]);
        __half hraw[BF];
        #pragma unroll
        for (int t = 0; t < BF; ++t)
            hraw[t] = h[(size_t)sid[t] * 64 + j];
        int4 eav[BF];
        #pragma unroll
        for (int t = 0; t < BF; ++t)
            eav[t] = *(const int4*)&ea16[(size_t)idxs[t] * 8];

        #pragma unroll
        for (int t = 0; t < BF; ++t) {
            __half2 d = __hmul2(u2h(eav[t].x), w2[0]);
            d = __hfma2(u2h(eav[t].y), w2[1], d);
            d = __hfma2(u2h(eav[t].z), w2[2], d);
            d = __hfma2(u2h(eav[t].w), w2[3], d);
            float proj = __half2float(__low2half(d)) + __half2float(__high2half(d));
            float m = __half2float(hraw[t]) + proj + bej;
            float r = m > 0.0f ? m : 0.0f;
            acc += (t < cnt) ? r : 0.0f;
        }
    }
    xs[(size_t)n * 64 + j] = __float2half(acc);
}

// ===========================================================================
// Node GEMM on matrix cores: out = relu(xs @ W + b), fp16 in/out, fp32 acc.
// v_mfma_f32_16x16x32_f16. One wave = 32 nodes (two 16-row tiles sharing
// each Wt fragment load) x 128 features. 4 waves/block -> 128 nodes/block.
// ===========================================================================
template<int K>
__global__ __launch_bounds__(256) void node_mfma_kernel(
    const _Float16* __restrict__ xs,   // [N,K] fp16
    const _Float16* __restrict__ Wt,   // [128][K] fp16 (W transposed)
    const float*    __restrict__ b,    // [128]
    _Float16*       __restrict__ out,  // [N,128] fp16
    int N)
{
    int wave  = threadIdx.x >> 6;             // 0..3
    int lane  = threadIdx.x & 63;
    int row16 = lane & 15;
    int quad  = lane >> 4;
    int m0    = (blockIdx.x * 4 + wave) * 32; // node base of this wave (2 tiles)

    int nA = m0 + row16;        if (nA >= N) nA = N - 1;
    int nB = m0 + 16 + row16;   if (nB >= N) nB = N - 1;

    floatx4 accA[8], accB[8];
    #pragma unroll
    for (int t = 0; t < 8; ++t) { accA[t] = (floatx4)(0.0f); accB[t] = (floatx4)(0.0f); }

    #pragma unroll
    for (int kc = 0; kc < K; kc += 32) {
        half8 a0 = *(const half8*)&xs[(size_t)nA * K + kc + quad * 8];
        half8 a1 = *(const half8*)&xs[(size_t)nB * K + kc + quad * 8];
        #pragma unroll
        for (int t = 0; t < 8; ++t) {
            half8 bf = *(const half8*)&Wt[(size_t)(t * 16 + row16) * K + kc + quad * 8];
            accA[t] = __builtin_amdgcn_mfma_f32_16x16x32_f16(a0, bf, accA[t], 0, 0, 0);
            accB[t] = __builtin_amdgcn_mfma_f32_16x16x32_f16(a1, bf, accB[t], 0, 0, 0);
        }
    }

    #pragma unroll
    for (int t = 0; t < 8; ++t) {
        int col = t * 16 + row16;             // output feature
        float bj = b[col];
        #pragma unroll
        for (int r = 0; r < 4; ++r) {
            int nodeA = m0 + quad * 4 + r;
            if (nodeA < N) {
                float v = accA[t][r] + bj;
                out[(size_t)nodeA * 128 + col] = (_Float16)(v > 0.0f ? v : 0.0f);
            }
            int nodeB = m0 + 16 + quad * 4 + r;
            if (nodeB < N) {
                float v = accB[t][r] + bj;
                out[(size_t)nodeB * 128 + col] = (_Float16)(v > 0.0f ? v : 0.0f);
            }
        }
    }
}

// ===========================================================================
// Pool: batch sorted -> one block per graph, binary-search range, direct sum.
// ===========================================================================
__global__ __launch_bounds__(128) void pool_kernel(
    const __half* __restrict__ h,      // [N, 128] fp16
    const int*    __restrict__ batch,  // [N] sorted
    float*        __restrict__ out,    // [G, 128]
    int N)
{
    __shared__ int s_lo, s_hi;
    int g = blockIdx.x;
    int j = threadIdx.x;

    if (j == 0) {
        int lo = 0, hi = N;
        while (lo < hi) { int m = (lo + hi) >> 1; if (batch[m] < g) lo = m + 1; else hi = m; }
        s_lo = lo;
        int lo2 = lo, hi2 = N;
        while (lo2 < hi2) { int m = (lo2 + hi2) >> 1; if (batch[m] < g + 1) lo2 = m + 1; else hi2 = m; }
        s_hi = lo2;
    }
    __syncthreads();

    int lo = s_lo, hi = s_hi;
    float acc = 0.0f;
    #pragma unroll 4
    for (int n = lo; n < hi; ++n) {
        acc += __half2float(h[(size_t)n * HIDDEN + j]);
    }
    float c = (float)(hi - lo);
    out[g * HIDDEN + j] = acc / (c > 1.0f ? c : 1.0f);
}

// ===========================================================================
extern "C" void kernel_launch(void* const* d_in, const int* in_sizes, int n_in,
                              void* d_out, int out_size, void* d_ws, size_t ws_size,
                              hipStream_t stream)
{
    const float* x   = (const float*)d_in[0];      // [N, 64]
    const int*   ei  = (const int*)d_in[1];        // [2, E]
    const float* ea  = (const float*)d_in[2];      // [E, 8]
    const int*   bat = (const int*)d_in[3];        // [N]
    const float* W1  = (const float*)d_in[4];
    const float* b1  = (const float*)d_in[5];
    const float* We1 = (const float*)d_in[6];
    const float* be1 = (const float*)d_in[7];
    const float* W2  = (const float*)d_in[8];
    const float* b2  = (const float*)d_in[9];
    const float* We2 = (const float*)d_in[10];
    const float* be2 = (const float*)d_in[11];
    const float* W3  = (const float*)d_in[12];
    const float* b3  = (const float*)d_in[13];
    const float* We3 = (const float*)d_in[14];
    const float* be3 = (const float*)d_in[15];
    float* out = (float*)d_out;

    const int* src = ei;
    const int* dst = ei + N_EDGES;

    // ---------------- workspace layout ----------------
    int* deg       = (int*)d_ws;                             // [N]
    int* rowptr    = deg + N_NODES;                          // [N]
    int* pos       = rowptr + N_NODES;                       // [N]
    int* eid       = pos + N_NODES;                          // [E]
    int* src_s     = eid + N_EDGES;                          // [E]
    int* blockSums = src_s + N_EDGES;                        // [128]
    __half* ea16   = (__half*)(blockSums + 128);             // [E, 8] fp16
    __half* xs     = ea16 + (size_t)N_EDGES * EDGE_DIM;      // [N,128] fp16
    __half* xh     = xs + (size_t)N_NODES * HIDDEN;          // [N, 64] fp16
    __half* h1h    = xh + (size_t)N_NODES * IN_CH;           // [N, 128] fp16
    __half* h2h    = h1h + (size_t)N_NODES * HIDDEN;         // [N, 128] fp16
    _Float16* Wt1  = (_Float16*)(h2h + (size_t)N_NODES * HIDDEN); // [128,64]
    _Float16* Wt2  = Wt1 + 128 * IN_CH;                      // [128,128]
    _Float16* Wt3  = Wt2 + 128 * HIDDEN;                     // [128,128]

    const int BLK = 256;
    const int NB_E = (N_EDGES + BLK - 1) / BLK;
    const int NB_N = (N_NODES + BLK - 1) / BLK;
    const int SCAN_B = (N_NODES + 511) / 512;    // 98
    const int MFMA_B = (N_NODES + 127) / 128;    // 391 blocks (4 waves x 32 nodes)
    const int WT_ELEMS = 128 * IN_CH + 2 * 128 * HIDDEN;

    // ---------------- deterministic CSR build + weight prep ----------------
    hipMemsetAsync(deg, 0, N_NODES * sizeof(int), stream);
    hist_kernel<<<NB_E, BLK, 0, stream>>>(dst, deg, N_EDGES);
    scan1_kernel<<<SCAN_B, 256, 0, stream>>>(deg, pos, blockSums, N_NODES);
    scan2_kernel<<<1, 128, 0, stream>>>(blockSums, SCAN_B);
    scan3_kernel<<<NB_N, BLK, 0, stream>>>(pos, deg, blockSums, rowptr, pos, N_NODES);
    scatter_kernel<<<NB_E, BLK, 0, stream>>>(dst, pos, eid, N_EDGES);
    segsort_kernel<<<NB_N, BLK, 0, stream>>>(eid, rowptr, deg, N_NODES);   // canonical order
    edge_gather_kernel<<<NB_E, BLK, 0, stream>>>(eid, src, ea, src_s, ea16, N_EDGES);
    cvt_half_kernel<<<(N_NODES * IN_CH + BLK - 1) / BLK, BLK, 0, stream>>>(x, xh, N_NODES * IN_CH);
    cvt_wt_all_kernel<<<(WT_ELEMS + BLK - 1) / BLK, BLK, 0, stream>>>(W1, W2, W3, Wt1, Wt2, Wt3);

    // ---------------- layer 1 (64 -> 128) ----------------
    gather_xs64_kernel<<<N_NODES, 64, 0, stream>>>(
        xh, src_s, ea16, rowptr, deg, We1, be1, xs, N_NODES);
    node_mfma_kernel<IN_CH><<<MFMA_B, 256, 0, stream>>>(
        (const _Float16*)xs, Wt1, b1, (_Float16*)h1h, N_NODES);

    // ---------------- layer 2 (128 -> 128) ----------------
    gather_xs128_kernel<<<N_NODES, 64, 0, stream>>>(
        h1h, src_s, ea16, rowptr, deg, We2, be2, xs, N_NODES);
    node_mfma_kernel<HIDDEN><<<MFMA_B, 256, 0, stream>>>(
        (const _Float16*)xs, Wt2, b2, (_Float16*)h2h, N_NODES);

    // ---------------- layer 3 (128 -> 128) ----------------
    gather_xs128_kernel<<<N_NODES, 64, 0, stream>>>(
        h2h, src_s, ea16, rowptr, deg, We3, be3, xs, N_NODES);
    node_mfma_kernel<HIDDEN><<<MFMA_B, 256, 0, stream>>>(
        (const _Float16*)xs, Wt3, b3, (_Float16*)h1h, N_NODES);

    // ---------------- global mean pool ----------------
    pool_kernel<<<NUM_GRAPHS, 128, 0, stream>>>(h1h, bat, out, N_NODES);
}

// Round 11
// 462.020 us; speedup vs baseline: 1.4282x; 1.0135x over previous
//
#include <hip/hip_runtime.h>
#include <hip/hip_bf16.h>
#include <hip/hip_fp16.h>

#define N_NODES 50000
#define N_EDGES 800000
#define IN_CH 64
#define EDGE_DIM 8
#define HIDDEN 128
#define NUM_GRAPHS 256
#define NPASS 8
#define PASS_W ((N_NODES + NPASS - 1) / NPASS)   // 6250

typedef __attribute__((ext_vector_type(8))) _Float16 half8;
typedef __attribute__((ext_vector_type(4))) float floatx4;

static __device__ __forceinline__ __half2 u2h(int u) {
    union { int i; __half2 h; } cv; cv.i = u; return cv.h;
}

// ===========================================================================
// CSR build: histogram, scan, then 8 dst-range scatter passes that write the
// final (src, ea fp16) records directly. Order within a node is atomic-
// nondeterministic; the gathers use DOUBLE accumulation so the sum is
// order-insensitive to ~2^-53 — far below fp16 rounding visibility.
// ===========================================================================
__global__ __launch_bounds__(256) void hist_kernel(
    const int* __restrict__ dst, int* __restrict__ deg, int E)
{
    int i = blockIdx.x * blockDim.x + threadIdx.x;
    if (i < E) atomicAdd(&deg[dst[i]], 1);
}

__global__ __launch_bounds__(256) void scan1_kernel(
    const int* __restrict__ deg, int* __restrict__ incl,
    int* __restrict__ blockSums, int N)
{
    __shared__ int s[256];
    int b = blockIdx.x, t = threadIdx.x;
    int i0 = b * 512 + 2 * t;
    int a0 = (i0 < N) ? deg[i0] : 0;
    int a1 = (i0 + 1 < N) ? deg[i0 + 1] : 0;
    int ps = a0 + a1;
    s[t] = ps;
    __syncthreads();
    for (int off = 1; off < 256; off <<= 1) {
        int v = (t >= off) ? s[t - off] : 0;
        __syncthreads();
        s[t] += v;
        __syncthreads();
    }
    int exclp = s[t] - ps;
    if (i0 < N)     incl[i0]     = exclp + a0;
    if (i0 + 1 < N) incl[i0 + 1] = exclp + a0 + a1;
    if (t == 255) blockSums[b] = s[255];
}

__global__ __launch_bounds__(128) void scan2_kernel(int* __restrict__ blockSums, int B)
{
    __shared__ int s[128];
    int t = threadIdx.x;
    int v = (t < B) ? blockSums[t] : 0;
    s[t] = v;
    __syncthreads();
    for (int off = 1; off < 128; off <<= 1) {
        int u = (t >= off) ? s[t - off] : 0;
        __syncthreads();
        s[t] += u;
        __syncthreads();
    }
    if (t < B) blockSums[t] = s[t] - v;   // exclusive
}

__global__ __launch_bounds__(256) void scan3_kernel(
    const int* __restrict__ incl, const int* __restrict__ deg,
    const int* __restrict__ blockSums, int* __restrict__ rowptr,
    int* __restrict__ pos, int N)
{
    int i = blockIdx.x * blockDim.x + threadIdx.x;
    if (i >= N) return;
    int v = incl[i] - deg[i] + blockSums[i >> 9];
    rowptr[i] = v;
    pos[i] = v;
}

// One dst-range pass: only edges with dst in [lo, lo+PASS_W) are placed.
// Keeps the written region ~2 MB -> write lines fill before eviction.
__global__ __launch_bounds__(256) void scatter_pass_kernel(
    const int* __restrict__ dst, const int* __restrict__ src,
    const float* __restrict__ ea, int* __restrict__ pos,
    int* __restrict__ src_s, __half* __restrict__ ea16, int lo, int E)
{
    int e = blockIdx.x * blockDim.x + threadIdx.x;
    if (e >= E) return;
    int d = dst[e];
    if ((unsigned)(d - lo) >= (unsigned)PASS_W) return;
    int p = atomicAdd(&pos[d], 1);
    src_s[p] = src[e];
    const float4* q = (const float4*)(ea + (size_t)e * EDGE_DIM);
    float4 a = q[0], b = q[1];
    __half2* o = (__half2*)(ea16 + (size_t)p * EDGE_DIM);
    o[0] = __floats2half2_rn(a.x, a.y);
    o[1] = __floats2half2_rn(a.z, a.w);
    o[2] = __floats2half2_rn(b.x, b.y);
    o[3] = __floats2half2_rn(b.z, b.w);
}

// fp32 -> fp16 conversion (x input)
__global__ __launch_bounds__(256) void cvt_half_kernel(
    const float* __restrict__ x, __half* __restrict__ xh, int n)
{
    int i = blockIdx.x * blockDim.x + threadIdx.x;
    if (i < n) xh[i] = __float2half(x[i]);
}

// All three W [K][128] fp32 -> Wt [128][K] fp16 in one dispatch.
__global__ __launch_bounds__(256) void cvt_wt_all_kernel(
    const float* __restrict__ W1, const float* __restrict__ W2,
    const float* __restrict__ W3,
    _Float16* __restrict__ Wt1, _Float16* __restrict__ Wt2,
    _Float16* __restrict__ Wt3)
{
    int idx = blockIdx.x * blockDim.x + threadIdx.x;
    if (idx < 128 * IN_CH) {
        int n = idx / IN_CH, k = idx - n * IN_CH;
        Wt1[idx] = (_Float16)W1[k * 128 + n];
        return;
    }
    idx -= 128 * IN_CH;
    if (idx < 128 * HIDDEN) {
        int n = idx / HIDDEN, k = idx - n * HIDDEN;
        Wt2[idx] = (_Float16)W2[k * 128 + n];
        return;
    }
    idx -= 128 * HIDDEN;
    if (idx < 128 * HIDDEN) {
        int n = idx / HIDDEN, k = idx - n * HIDDEN;
        Wt3[idx] = (_Float16)W3[k * 128 + n];
    }
}

// ===========================================================================
// Gather-aggregate, batched (8 edges in flight), packed-fp16 message math,
// DOUBLE accumulation (order-insensitive sum -> deterministic-enough output).
//   xs[n][j] = h[n][j] + sum_e relu( h[src][j] + (ea@We+be)[j] )
// ===========================================================================
#define BF 8   // edges in flight per wave

__global__ __launch_bounds__(64) void gather_xs128_kernel(
    const __half* __restrict__ h,       // [N,128] fp16
    const int*    __restrict__ src_s,   // [E] CSR order
    const __half* __restrict__ ea16,    // [E,8] fp16 CSR order
    const int*    __restrict__ rowptr,  // [N]
    const int*    __restrict__ deg,     // [N]
    const float*  __restrict__ We,      // [8,128]
    const float*  __restrict__ be,      // [128]
    __half*       __restrict__ xs,      // [N,128] fp16
    int N)
{
    int n  = blockIdx.x;
    int l  = threadIdx.x;       // 0..63
    int j0 = 2 * l;

    __half2 hw[8];
    #pragma unroll
    for (int k = 0; k < 8; ++k) {
        float2 wv = *(const float2*)&We[k * 128 + j0];
        hw[k] = __floats2half2_rn(wv.x, wv.y);
    }
    float2 bevf = *(const float2*)&be[j0];
    __half2 bev2 = __floats2half2_rn(bevf.x, bevf.y);

    int start = __builtin_amdgcn_readfirstlane(rowptr[n]);
    int dg    = __builtin_amdgcn_readfirstlane(deg[n]);
    int last  = start + dg - 1;

    float2 hf = __half22float2(*(const __half2*)&h[(size_t)n * 128 + j0]);
    double acc0 = (double)hf.x, acc1 = (double)hf.y;   // self term (eps = 0)

    for (int base = 0; base < dg; base += BF) {
        int cnt = dg - base;
        if (cnt > BF) cnt = BF;

        int idxs[BF];
        #pragma unroll
        for (int t = 0; t < BF; ++t) {
            int idx = start + base + t;
            idxs[t] = idx > last ? last : idx;
        }
        int sid[BF];
        #pragma unroll
        for (int t = 0; t < BF; ++t)
            sid[t] = __builtin_amdgcn_readfirstlane(src_s[idxs[t]]);
        __half2 hraw[BF];                 // random 4B/lane loads, latency hiders
        #pragma unroll
        for (int t = 0; t < BF; ++t)
            hraw[t] = *(const __half2*)&h[(size_t)sid[t] * 128 + j0];
        int4 eav[BF];                     // uniform 16B edge-attr loads
        #pragma unroll
        for (int t = 0; t < BF; ++t)
            eav[t] = *(const int4*)&ea16[(size_t)idxs[t] * 8];

        #pragma unroll
        for (int t = 0; t < BF; ++t) {
            __half2 e01 = u2h(eav[t].x), e23 = u2h(eav[t].y);
            __half2 e45 = u2h(eav[t].z), e67 = u2h(eav[t].w);
            __half2 m = __hfma2(__low2half2(e01),  hw[0], bev2);
            m = __hfma2(__high2half2(e01), hw[1], m);
            m = __hfma2(__low2half2(e23),  hw[2], m);
            m = __hfma2(__high2half2(e23), hw[3], m);
            m = __hfma2(__low2half2(e45),  hw[4], m);
            m = __hfma2(__high2half2(e45), hw[5], m);
            m = __hfma2(__low2half2(e67),  hw[6], m);
            m = __hfma2(__high2half2(e67), hw[7], m);
            m = __hadd2(m, hraw[t]);
            float2 mf = __half22float2(m);
            double r0 = (double)(mf.x > 0.0f ? mf.x : 0.0f);
            double r1 = (double)(mf.y > 0.0f ? mf.y : 0.0f);
            acc0 += (t < cnt) ? r0 : 0.0;
            acc1 += (t < cnt) ? r1 : 0.0;
        }
    }
    *(__half2*)&xs[(size_t)n * 128 + j0] =
        __floats2half2_rn((float)acc0, (float)acc1);
}

// D=64: 1 feature/lane; projection via k-packed fp16 dot; double accumulate.
__global__ __launch_bounds__(64) void gather_xs64_kernel(
    const __half* __restrict__ h,       // [N,64] fp16
    const int*    __restrict__ src_s,
    const __half* __restrict__ ea16,    // [E,8] fp16
    const int*    __restrict__ rowptr,
    const int*    __restrict__ deg,
    const float*  __restrict__ We,      // [8,64]
    const float*  __restrict__ be,      // [64]
    __half*       __restrict__ xs,      // [N,64] fp16
    int N)
{
    int n = blockIdx.x;
    int j = threadIdx.x;   // 0..63

    __half2 w2[4];
    #pragma unroll
    for (int p = 0; p < 4; ++p)
        w2[p] = __floats2half2_rn(We[(2 * p) * 64 + j], We[(2 * p + 1) * 64 + j]);
    float bej = be[j];

    int start = __builtin_amdgcn_readfirstlane(rowptr[n]);
    int dg    = __builtin_amdgcn_readfirstlane(deg[n]);
    int last  = start + dg - 1;

    double acc = (double)__half2float(h[(size_t)n * 64 + j]);   // self term

    for (int base = 0; base < dg; base += BF) {
        int cnt = dg - base;
        if (cnt > BF) cnt = BF;

        int idxs[BF];
        #pragma unroll
        for (int t = 0; t < BF; ++t) {
            int idx = start + base + t;
            idxs[t] = idx > last ? last : idx;
        }
        int sid[BF];
        #pragma unroll
        for (int t = 0; t < BF; ++t)
            sid[t] = __builtin_amdgcn_readfirstlane(src_s[idxs[t]]);
        __half hraw[BF];
        #pragma unroll
        for (int t = 0; t < BF; ++t)
            hraw[t] = h[(size_t)sid[t] * 64 + j];
        int4 eav[BF];
        #pragma unroll
        for (int t = 0; t < BF; ++t)
            eav[t] = *(const int4*)&ea16[(size_t)idxs[t] * 8];

        #pragma unroll
        for (int t = 0; t < BF; ++t) {
            __half2 d = __hmul2(u2h(eav[t].x), w2[0]);
            d = __hfma2(u2h(eav[t].y), w2[1], d);
            d = __hfma2(u2h(eav[t].z), w2[2], d);
            d = __hfma2(u2h(eav[t].w), w2[3], d);
            float proj = __half2float(__low2half(d)) + __half2float(__high2half(d));
            float m = __half2float(hraw[t]) + proj + bej;
            double r = (double)(m > 0.0f ? m : 0.0f);
            acc += (t < cnt) ? r : 0.0;
        }
    }
    xs[(size_t)n * 64 + j] = __float2half((float)acc);
}

// ===========================================================================
// Node GEMM on matrix cores: out = relu(xs @ W + b), fp16 in/out, fp32 acc.
// One wave = 32 nodes (two 16-row tiles sharing each Wt fragment load).
// ===========================================================================
template<int K>
__global__ __launch_bounds__(256) void node_mfma_kernel(
    const _Float16* __restrict__ xs,   // [N,K] fp16
    const _Float16* __restrict__ Wt,   // [128][K] fp16 (W transposed)
    const float*    __restrict__ b,    // [128]
    _Float16*       __restrict__ out,  // [N,128] fp16
    int N)
{
    int wave  = threadIdx.x >> 6;             // 0..3
    int lane  = threadIdx.x & 63;
    int row16 = lane & 15;
    int quad  = lane >> 4;
    int m0    = (blockIdx.x * 4 + wave) * 32;

    int nA = m0 + row16;        if (nA >= N) nA = N - 1;
    int nB = m0 + 16 + row16;   if (nB >= N) nB = N - 1;

    floatx4 accA[8], accB[8];
    #pragma unroll
    for (int t = 0; t < 8; ++t) { accA[t] = (floatx4)(0.0f); accB[t] = (floatx4)(0.0f); }

    #pragma unroll
    for (int kc = 0; kc < K; kc += 32) {
        half8 a0 = *(const half8*)&xs[(size_t)nA * K + kc + quad * 8];
        half8 a1 = *(const half8*)&xs[(size_t)nB * K + kc + quad * 8];
        #pragma unroll
        for (int t = 0; t < 8; ++t) {
            half8 bf = *(const half8*)&Wt[(size_t)(t * 16 + row16) * K + kc + quad * 8];
            accA[t] = __builtin_amdgcn_mfma_f32_16x16x32_f16(a0, bf, accA[t], 0, 0, 0);
            accB[t] = __builtin_amdgcn_mfma_f32_16x16x32_f16(a1, bf, accB[t], 0, 0, 0);
        }
    }

    #pragma unroll
    for (int t = 0; t < 8; ++t) {
        int col = t * 16 + row16;
        float bj = b[col];
        #pragma unroll
        for (int r = 0; r < 4; ++r) {
            int nodeA = m0 + quad * 4 + r;
            if (nodeA < N) {
                float v = accA[t][r] + bj;
                out[(size_t)nodeA * 128 + col] = (_Float16)(v > 0.0f ? v : 0.0f);
            }
            int nodeB = m0 + 16 + quad * 4 + r;
            if (nodeB < N) {
                float v = accB[t][r] + bj;
                out[(size_t)nodeB * 128 + col] = (_Float16)(v > 0.0f ? v : 0.0f);
            }
        }
    }
}

// ===========================================================================
// Pool: batch sorted -> one block per graph, binary-search range, direct sum.
// ===========================================================================
__global__ __launch_bounds__(128) void pool_kernel(
    const __half* __restrict__ h,      // [N, 128] fp16
    const int*    __restrict__ batch,  // [N] sorted
    float*        __restrict__ out,    // [G, 128]
    int N)
{
    __shared__ int s_lo, s_hi;
    int g = blockIdx.x;
    int j = threadIdx.x;

    if (j == 0) {
        int lo = 0, hi = N;
        while (lo < hi) { int m = (lo + hi) >> 1; if (batch[m] < g) lo = m + 1; else hi = m; }
        s_lo = lo;
        int lo2 = lo, hi2 = N;
        while (lo2 < hi2) { int m = (lo2 + hi2) >> 1; if (batch[m] < g + 1) lo2 = m + 1; else hi2 = m; }
        s_hi = lo2;
    }
    __syncthreads();

    int lo = s_lo, hi = s_hi;
    float acc = 0.0f;
    #pragma unroll 4
    for (int n = lo; n < hi; ++n) {
        acc += __half2float(h[(size_t)n * HIDDEN + j]);
    }
    float c = (float)(hi - lo);
    out[g * HIDDEN + j] = acc / (c > 1.0f ? c : 1.0f);
}

// ===========================================================================
extern "C" void kernel_launch(void* const* d_in, const int* in_sizes, int n_in,
                              void* d_out, int out_size, void* d_ws, size_t ws_size,
                              hipStream_t stream)
{
    const float* x   = (const float*)d_in[0];      // [N, 64]
    const int*   ei  = (const int*)d_in[1];        // [2, E]
    const float* ea  = (const float*)d_in[2];      // [E, 8]
    const int*   bat = (const int*)d_in[3];        // [N]
    const float* W1  = (const float*)d_in[4];
    const float* b1  = (const float*)d_in[5];
    const float* We1 = (const float*)d_in[6];
    const float* be1 = (const float*)d_in[7];
    const float* W2  = (const float*)d_in[8];
    const float* b2  = (const float*)d_in[9];
    const float* We2 = (const float*)d_in[10];
    const float* be2 = (const float*)d_in[11];
    const float* W3  = (const float*)d_in[12];
    const float* b3  = (const float*)d_in[13];
    const float* We3 = (const float*)d_in[14];
    const float* be3 = (const float*)d_in[15];
    float* out = (float*)d_out;

    const int* src = ei;
    const int* dst = ei + N_EDGES;

    // ---------------- workspace layout ----------------
    int* deg       = (int*)d_ws;                             // [N]
    int* rowptr    = deg + N_NODES;                          // [N]
    int* pos       = rowptr + N_NODES;                       // [N]
    int* src_s     = pos + N_NODES;                          // [E]
    int* blockSums = src_s + N_EDGES;                        // [128]
    __half* ea16   = (__half*)(blockSums + 128);             // [E, 8] fp16
    __half* xs     = ea16 + (size_t)N_EDGES * EDGE_DIM;      // [N,128] fp16
    __half* xh     = xs + (size_t)N_NODES * HIDDEN;          // [N, 64] fp16
    __half* h1h    = xh + (size_t)N_NODES * IN_CH;           // [N, 128] fp16
    __half* h2h    = h1h + (size_t)N_NODES * HIDDEN;         // [N, 128] fp16
    _Float16* Wt1  = (_Float16*)(h2h + (size_t)N_NODES * HIDDEN); // [128,64]
    _Float16* Wt2  = Wt1 + 128 * IN_CH;                      // [128,128]
    _Float16* Wt3  = Wt2 + 128 * HIDDEN;                     // [128,128]

    const int BLK = 256;
    const int NB_E = (N_EDGES + BLK - 1) / BLK;
    const int NB_N = (N_NODES + BLK - 1) / BLK;
    const int SCAN_B = (N_NODES + 511) / 512;    // 98
    const int MFMA_B = (N_NODES + 127) / 128;    // 391
    const int WT_ELEMS = 128 * IN_CH + 2 * 128 * HIDDEN;

    // ---------------- CSR build (8 dst-range scatter passes) ----------------
    hipMemsetAsync(deg, 0, N_NODES * sizeof(int), stream);
    hist_kernel<<<NB_E, BLK, 0, stream>>>(dst, deg, N_EDGES);
    scan1_kernel<<<SCAN_B, 256, 0, stream>>>(deg, pos, blockSums, N_NODES);
    scan2_kernel<<<1, 128, 0, stream>>>(blockSums, SCAN_B);
    scan3_kernel<<<NB_N, BLK, 0, stream>>>(pos, deg, blockSums, rowptr, pos, N_NODES);
    for (int pass = 0; pass < NPASS; ++pass) {
        scatter_pass_kernel<<<NB_E, BLK, 0, stream>>>(
            dst, src, ea, pos, src_s, ea16, pass * PASS_W, N_EDGES);
    }
    cvt_half_kernel<<<(N_NODES * IN_CH + BLK - 1) / BLK, BLK, 0, stream>>>(x, xh, N_NODES * IN_CH);
    cvt_wt_all_kernel<<<(WT_ELEMS + BLK - 1) / BLK, BLK, 0, stream>>>(W1, W2, W3, Wt1, Wt2, Wt3);

    // ---------------- layer 1 (64 -> 128) ----------------
    gather_xs64_kernel<<<N_NODES, 64, 0, stream>>>(
        xh, src_s, ea16, rowptr, deg, We1, be1, xs, N_NODES);
    node_mfma_kernel<IN_CH><<<MFMA_B, 256, 0, stream>>>(
        (const _Float16*)xs, Wt1, b1, (_Float16*)h1h, N_NODES);

    // ---------------- layer 2 (128 -> 128) ----------------
    gather_xs128_kernel<<<N_NODES, 64, 0, stream>>>(
        h1h, src_s, ea16, rowptr, deg, We2, be2, xs, N_NODES);
    node_mfma_kernel<HIDDEN><<<MFMA_B, 256, 0, stream>>>(
        (const _Float16*)xs, Wt2, b2, (_Float16*)h2h, N_NODES);

    // ---------------- layer 3 (128 -> 128) ----------------
    gather_xs128_kernel<<<N_NODES, 64, 0, stream>>>(
        h2h, src_s, ea16, rowptr, deg, We3, be3, xs, N_NODES);
    node_mfma_kernel<HIDDEN><<<MFMA_B, 256, 0, stream>>>(
        (const _Float16*)xs, Wt3, b3, (_Float16*)h1h, N_NODES);

    // ---------------- global mean pool ----------------
    pool_kernel<<<NUM_GRAPHS, 128, 0, stream>>>(h1h, bat, out, N_NODES);
}